// Round 4
// baseline (1632.834 us; speedup 1.0000x reference)
//
#include <hip/hip_runtime.h>

#define BB 32
#define NPTS0 2048
#define KNB 16
#define KC 256   // key-chunk size for two-pass kNN

constexpr int ilog2c(int n){ int l=0; while(n>1){ n>>=1; ++l; } return l; }

static __device__ __forceinline__ float sq3(float a, float b, float c){
  return __fadd_rn(__fadd_rn(__fmul_rn(a,a),__fmul_rn(b,b)),__fmul_rn(c,c));
}

// ---------------- input projection: f0[b][n][o] = w_in(8x3) @ x + b_in ----------------
__global__ __launch_bounds__(256) void proj_kernel(const float* __restrict__ x,
    const float* __restrict__ w, const float* __restrict__ bias, float* __restrict__ f0)
{
  int gid = blockIdx.x*256 + threadIdx.x;
  if (gid >= BB*NPTS0) return;
  float x0 = x[gid*3+0], x1 = x[gid*3+1], x2 = x[gid*3+2];
  #pragma unroll
  for (int o = 0; o < 8; ++o){
    float acc = __fmul_rn(w[o*3+0], x0);
    acc = __fmaf_rn(w[o*3+1], x1, acc);
    acc = __fmaf_rn(w[o*3+2], x2, acc);
    f0[gid*8+o] = __fadd_rn(acc, bias[o]);
  }
}

// ---------------- kNN pass 1: per 256-key chunk, local top-16 ----------------
__global__ __launch_bounds__(256) void knn_part_kernel(const float* __restrict__ qpts,
    const float* __restrict__ kpts, int Nq, int Nk,
    float* __restrict__ pd, unsigned char* __restrict__ pi)
{
  __shared__ float4 kk4[KC];
  int b = blockIdx.x, tid = threadIdx.x;
  int kc = blockIdx.z, nkc = gridDim.z;
  {
    int j = kc*KC + tid;                 // Nk is always a multiple of 256
    float a = kpts[(b*Nk+j)*3+0];
    float c = kpts[(b*Nk+j)*3+1];
    float d = kpts[(b*Nk+j)*3+2];
    kk4[tid] = make_float4(a, c, d, sq3(a,c,d));
  }
  __syncthreads();
  int q = blockIdx.y*256 + tid;
  if (q >= Nq) return;
  float qx = qpts[(b*Nq+q)*3+0], qy = qpts[(b*Nq+q)*3+1], qz = qpts[(b*Nq+q)*3+2];
  float qq = sq3(qx,qy,qz);
  float th[KNB]; int ti[KNB];
  #pragma unroll
  for (int i=0;i<KNB;i++){ th[i] = __builtin_inff(); ti[i] = 0; }
  for (int j=0;j<KC;j++){
    float4 k4 = kk4[j];
    float dot = __fmul_rn(qx,k4.x);
    dot = __fmaf_rn(qy,k4.y,dot);
    dot = __fmaf_rn(qz,k4.z,dot);
    float d = __fadd_rn(__fsub_rn(qq, __fmul_rn(2.0f,dot)), k4.w);
    if (d < th[KNB-1]){                   // strict <: equal dist keeps earlier index
      th[KNB-1] = d; ti[KNB-1] = j;
      #pragma unroll
      for (int i=KNB-1;i>0;--i){
        if (th[i] < th[i-1]){
          float tv=th[i]; th[i]=th[i-1]; th[i-1]=tv;
          int tj=ti[i]; ti[i]=ti[i-1]; ti[i-1]=tj;
        }
      }
    }
  }
  size_t base = ((size_t)(b*Nq+q)*nkc + kc)*KNB;
  #pragma unroll
  for (int i=0;i<KNB;i++){ pd[base+i] = th[i]; pi[base+i] = (unsigned char)ti[i]; }
}

// ---------------- kNN pass 2: merge per-chunk sorted candidate lists ----------------
__global__ __launch_bounds__(256) void knn_merge_kernel(const float* __restrict__ pd,
    const unsigned char* __restrict__ pi, int Nq, int nkc, int* __restrict__ oidx)
{
  int gid = blockIdx.x*256 + threadIdx.x;
  if (gid >= BB*Nq) return;               // gid = b*Nq + q
  float th[KNB]; int ti[KNB];
  #pragma unroll
  for (int i=0;i<KNB;i++){ th[i] = __builtin_inff(); ti[i] = 0; }
  size_t base = (size_t)gid*nkc*KNB;
  for (int kc=0;kc<nkc;kc++){
    size_t cb = base + (size_t)kc*KNB;
    for (int i=0;i<KNB;i++){
      float d = pd[cb+i];
      if (d >= th[KNB-1]) break;           // chunk list sorted ascending
      int j = kc*KC + (int)pi[cb+i];
      th[KNB-1] = d; ti[KNB-1] = j;
      #pragma unroll
      for (int m=KNB-1;m>0;--m){
        if (th[m] < th[m-1]){
          float tv=th[m]; th[m]=th[m-1]; th[m-1]=tv;
          int tj=ti[m]; ti[m]=ti[m-1]; ti[m-1]=tj;
        }
      }
    }
  }
  #pragma unroll
  for (int i=0;i<KNB;i++) oidx[gid*KNB + i] = ti[i];
}

// ---------------- per-point GEMV: out[pn][o] = sum_c M[o][c]*fin[pn][c] ----------------
template<int C, int O, bool DIFF>
__global__ __launch_bounds__(256) void gemv_kernel(const float* __restrict__ fin,
    const float* __restrict__ W, float* __restrict__ out, int Npts)
{
  constexpr int NT = O/8;
  constexpr int LNT = ilog2c(NT);
  int gid = blockIdx.x*256 + threadIdx.x;
  if (gid >= BB*Npts*NT) return;
  int tile = gid & (NT-1);
  int pn = gid >> LNT;
  const float* frow = fin + pn*C;
  float f[C];
  #pragma unroll
  for (int c=0;c<C;c++) f[c] = frow[c];
  float acc[8];
  const float* wbase = W + (tile*8)*(2*C);
  #pragma unroll
  for (int oo=0;oo<8;oo++){
    const float* wrow = wbase + oo*(2*C);
    float a = 0.f;
    #pragma unroll
    for (int c=0;c<C;c++){
      float wv = DIFF ? __fsub_rn(wrow[C+c], wrow[c]) : wrow[c];
      a = __fmaf_rn(wv, f[c], a);
    }
    acc[oo] = a;
  }
  float* orow = out + pn*O + tile*8;
  #pragma unroll
  for (int oo=0;oo<8;oo++) orow[oo] = acc[oo];
}

// ---------------- GN stats pass: per (b,group) partial sum/sumsq of y = A[idx]+B --------
template<int O>
__global__ __launch_bounds__(256) void stats_kernel(const float* __restrict__ A,
    const float* __restrict__ Bq, const int* __restrict__ idx, int Nq, int Nk,
    double* __restrict__ part)
{
  constexpr int O4 = O/4;
  constexpr int LO4 = ilog2c(O4);
  int b = blockIdx.x, g = blockIdx.y, split = blockIdx.z;
  int nsplit = gridDim.z;
  int qlen = Nq / nsplit;
  int q0 = split * qlen;
  int tid = threadIdx.x;
  int total = qlen * KNB * O4;
  double s1 = 0.0, s2 = 0.0;
  for (int s = tid; s < total; s += 256){
    int oin = s & (O4-1);
    int rest = s >> LO4;
    int kk = rest & (KNB-1);
    int q = q0 + (rest >> 4);
    int j = idx[(b*Nq+q)*KNB + kk];
    float y = A[(b*Nk+j)*O + g*O4 + oin] + Bq[(b*Nq+q)*O + g*O4 + oin];
    s1 += (double)y;
    s2 += (double)y * (double)y;
  }
  #pragma unroll
  for (int m=32;m>0;m>>=1){ s1 += __shfl_down(s1,m); s2 += __shfl_down(s2,m); }
  __shared__ double sh1[4], sh2[4];
  int lane = tid & 63, w = tid >> 6;
  if (lane == 0){ sh1[w]=s1; sh2[w]=s2; }
  __syncthreads();
  if (tid == 0){
    double t1 = (sh1[0]+sh1[1])+(sh1[2]+sh1[3]);
    double t2 = (sh2[0]+sh2[1])+(sh2[2]+sh2[3]);
    int pi = (b*4+g)*nsplit + split;
    part[pi*2] = t1; part[pi*2+1] = t2;
  }
}

__global__ __launch_bounds__(128) void statsred_kernel(const double* __restrict__ part,
    int nsplit, double cnt, float* __restrict__ stats)
{
  int t = threadIdx.x;
  if (t >= BB*4) return;
  double s1=0.0, s2=0.0;
  for (int i=0;i<nsplit;i++){ s1 += part[(t*nsplit+i)*2]; s2 += part[(t*nsplit+i)*2+1]; }
  double mean = s1/cnt;
  double var = s2/cnt - mean*mean;
  double rstd = 1.0 / sqrt(var + 1e-5);
  stats[t*2] = (float)mean;
  stats[t*2+1] = (float)rstd;
}

// ---------------- final pass: normalize, gamma/beta, leaky, max over 16 neighbors ------
template<int O>
__global__ __launch_bounds__(256) void final_kernel(const float* __restrict__ A,
    const float* __restrict__ Bq, const int* __restrict__ idx,
    const float* __restrict__ stats, const float* __restrict__ gamma,
    const float* __restrict__ beta, float* __restrict__ fout, int Nq, int Nk)
{
  constexpr int LO = ilog2c(O);
  constexpr int LO4 = ilog2c(O/4);
  int b = blockIdx.y;
  int t = blockIdx.x*256 + threadIdx.x;
  if (t >= Nq*O) return;
  int o = t & (O-1);
  int q = t >> LO;
  int g = o >> LO4;
  float mu   = stats[(b*4+g)*2];
  float rstd = stats[(b*4+g)*2+1];
  float gam = gamma[o], bet = beta[o];
  float bq = Bq[(b*Nq+q)*O + o];
  const int* ip = idx + (b*Nq+q)*KNB;
  float m = -__builtin_inff();
  #pragma unroll
  for (int kk=0;kk<KNB;kk++){
    int j = ip[kk];
    float y = A[(b*Nk+j)*O + o] + bq;
    float yn = __fmul_rn(__fsub_rn(y, mu), rstd);
    float yv = __fadd_rn(__fmul_rn(yn, gam), bet);
    float l = yv >= 0.f ? yv : 0.2f*yv;
    m = fmaxf(m, l);
  }
  fout[(b*Nq+q)*O + o] = m;
}

// ---------------- farthest point sampling ------------------------------------------
// Packed-key argmax: key = (float_bits(dist) << 32) | ~idx. dist >= 0 so float bits
// are monotonic; max key = max dist with ties to LOWEST index (jnp.argmax semantics).
// Keys are unique (distinct idx) and always > 0, so the DPP bound_ctrl identity (0)
// can never win. The winning point's COORDS are carried through the reduce so no
// dependent LDS lookup is needed. Points live in registers (no LDS in update loop).
#define FPS_DPP5(CTRL, RM) { \
  unsigned slo = (unsigned)__builtin_amdgcn_update_dpp((int)blo,(int)blo, CTRL, RM, 0xF, true); \
  unsigned shi = (unsigned)__builtin_amdgcn_update_dpp((int)bhi,(int)bhi, CTRL, RM, 0xF, true); \
  unsigned sxu = (unsigned)__builtin_amdgcn_update_dpp((int)__float_as_uint(bcx),(int)__float_as_uint(bcx), CTRL, RM, 0xF, true); \
  unsigned syu = (unsigned)__builtin_amdgcn_update_dpp((int)__float_as_uint(bcy),(int)__float_as_uint(bcy), CTRL, RM, 0xF, true); \
  unsigned szu = (unsigned)__builtin_amdgcn_update_dpp((int)__float_as_uint(bcz),(int)__float_as_uint(bcz), CTRL, RM, 0xF, true); \
  unsigned long long a_ = ((unsigned long long)bhi<<32)|blo; \
  unsigned long long q_ = ((unsigned long long)shi<<32)|slo; \
  if (q_ > a_){ blo=slo; bhi=shi; bcx=__uint_as_float(sxu); bcy=__uint_as_float(syu); bcz=__uint_as_float(szu); } }

template<int NPT>   // points = NPT*256
__global__ __launch_bounds__(256) void fps_kernel(const float* __restrict__ pts,
    int S, int* __restrict__ oidx)
{
  constexpr int N = NPT*256;
  __shared__ __align__(16) float swp[2][4][8];   // [parity][wave][klo,khi,x,y,z,pad...]
  int b = blockIdx.x, tid = threadIdx.x;
  const float* P = pts + (size_t)b*N*3;
  // broadcast first point (L2-cached broadcast load)
  float c0x = P[0], c0y = P[1], c0z = P[2];
  // register-resident points + initial distances + initial local argmax
  float px[NPT], py[NPT], pz[NPT], dist[NPT];
  unsigned nlo[NPT];
  unsigned blo, bhi; float bcx, bcy, bcz;
  {
    unsigned long long bk = 0ull; float kx=0.f, ky=0.f, kz=0.f;
    #pragma unroll
    for (int t=0;t<NPT;t++){
      int i = t*256 + tid;
      px[t] = P[i*3+0]; py[t] = P[i*3+1]; pz[t] = P[i*3+2];
      nlo[t] = ~(unsigned)i;
      float dx = __fsub_rn(px[t], c0x);
      float dy = __fsub_rn(py[t], c0y);
      float dz = __fsub_rn(pz[t], c0z);
      float d = sq3(dx,dy,dz);
      dist[t] = d;
      unsigned long long k = ((unsigned long long)__float_as_uint(d)<<32) | nlo[t];
      if (k > bk){ bk = k; kx = px[t]; ky = py[t]; kz = pz[t]; }
    }
    blo = (unsigned)bk; bhi = (unsigned)(bk>>32);
    bcx = kx; bcy = ky; bcz = kz;
  }
  if (tid == 0) oidx[b*S+0] = 0;
  for (int s=1; s<S; ++s){
    // ---- wave-level DPP max-reduce (key + coords) -> lane 63 ----
    FPS_DPP5(0x111, 0xF)   // row_shr:1
    FPS_DPP5(0x112, 0xF)   // row_shr:2
    FPS_DPP5(0x114, 0xF)   // row_shr:4
    FPS_DPP5(0x118, 0xF)   // row_shr:8  -> lane15 of each row has row max
    FPS_DPP5(0x142, 0xA)   // row_bcast:15 into rows 1,3
    FPS_DPP5(0x143, 0xC)   // row_bcast:31 into rows 2,3 -> lane63 global
    int par = s & 1;
    if ((tid & 63) == 63){
      float4* wp = (float4*)&swp[par][tid>>6][0];
      *wp = make_float4(__uint_as_float(blo), __uint_as_float(bhi), bcx, bcy);
      swp[par][tid>>6][4] = bcz;
    }
    __syncthreads();                      // single barrier per iteration (parity dbuf)
    // ---- cross-wave merge of 4 (key,coords) partials (broadcast reads) ----
    float4 q0 = *(const float4*)&swp[par][0][0]; float z0 = swp[par][0][4];
    float4 q1 = *(const float4*)&swp[par][1][0]; float z1 = swp[par][1][4];
    float4 q2 = *(const float4*)&swp[par][2][0]; float z2 = swp[par][2][4];
    float4 q3 = *(const float4*)&swp[par][3][0]; float z3 = swp[par][3][4];
    unsigned long long k0 = ((unsigned long long)__float_as_uint(q0.y)<<32) | __float_as_uint(q0.x);
    unsigned long long k1 = ((unsigned long long)__float_as_uint(q1.y)<<32) | __float_as_uint(q1.x);
    unsigned long long k2 = ((unsigned long long)__float_as_uint(q2.y)<<32) | __float_as_uint(q2.x);
    unsigned long long k3 = ((unsigned long long)__float_as_uint(q3.y)<<32) | __float_as_uint(q3.x);
    if (k1 > k0){ k0 = k1; q0.z = q1.z; q0.w = q1.w; z0 = z1; }
    if (k3 > k2){ k2 = k3; q2.z = q3.z; q2.w = q3.w; z2 = z3; }
    if (k2 > k0){ k0 = k2; q0.z = q2.z; q0.w = q2.w; z0 = z2; }
    if (tid == 0) oidx[b*S+s] = (int)(~(unsigned)k0);
    float sx = q0.z, sy = q0.w, sz = z0;
    // ---- fused distance update + next-iteration local argmax (pure VALU) ----
    unsigned long long bk = 0ull; float kx=0.f, ky=0.f, kz=0.f;
    #pragma unroll
    for (int t=0;t<NPT;t++){
      float dx = __fsub_rn(px[t], sx);
      float dy = __fsub_rn(py[t], sy);
      float dz = __fsub_rn(pz[t], sz);
      float nd = sq3(dx,dy,dz);
      float d = fminf(dist[t], nd);
      dist[t] = d;
      unsigned long long k = ((unsigned long long)__float_as_uint(d)<<32) | nlo[t];
      if (k > bk){ bk = k; kx = px[t]; ky = py[t]; kz = pz[t]; }
    }
    blo = (unsigned)bk; bhi = (unsigned)(bk>>32);
    bcx = kx; bcy = ky; bcz = kz;
  }
}

// ---------------- gather coords + feats at fps indices --------------------------------
template<int C>
__global__ __launch_bounds__(256) void gather_kernel(const int* __restrict__ fidx,
    const float* __restrict__ pts, const float* __restrict__ fin,
    float* __restrict__ cq, float* __restrict__ fq, int Nin, int Nout)
{
  int gid = blockIdx.x*256 + threadIdx.x;
  if (gid >= BB*Nout) return;
  int b = gid / Nout;
  int i = gid - b*Nout;
  int src = fidx[b*Nout + i];
  #pragma unroll
  for (int c=0;c<3;c++) cq[gid*3+c] = pts[(b*Nin+src)*3+c];
  #pragma unroll
  for (int c=0;c<C;c++) fq[gid*C+c] = fin[(b*Nin+src)*C+c];
}

extern "C" void kernel_launch(void* const* d_in, const int* in_sizes, int n_in,
                              void* d_out, int out_size, void* d_ws, size_t ws_size,
                              hipStream_t stream)
{
  (void)in_sizes; (void)n_in; (void)out_size; (void)ws_size;
  const float* x    = (const float*)d_in[0];
  const float* w_in = (const float*)d_in[1];
  const float* b_in = (const float*)d_in[2];
  const float* w1 = (const float*)d_in[3];
  const float* g1 = (const float*)d_in[4];
  const float* be1= (const float*)d_in[5];
  const float* w2 = (const float*)d_in[6];
  const float* g2 = (const float*)d_in[7];
  const float* be2= (const float*)d_in[8];
  const float* w3 = (const float*)d_in[9];
  const float* g3 = (const float*)d_in[10];
  const float* be3= (const float*)d_in[11];
  const float* w4 = (const float*)d_in[12];
  const float* g4 = (const float*)d_in[13];
  const float* be4= (const float*)d_in[14];

  float* out = (float*)d_out;
  float* coor_out = out;                    // (32,128,3)
  float* f_out = out + BB*128*3;            // (32,128,256)

  char* ws = (char*)d_ws;
  size_t off = 0;
  auto alloc = [&](size_t bytes)->void*{ void* p = ws + off; off += (bytes + 255) & ~(size_t)255; return p; };

  // ---- persistent buffers ----
  float* f0     = (float*)alloc((size_t)BB*2048*8*4);
  int*   idx1   = (int*)  alloc((size_t)BB*2048*16*4);
  float* f1     = (float*)alloc((size_t)BB*2048*32*4);
  double* part  = (double*)alloc((size_t)BB*4*8*2*8);
  float* statsv = (float*)alloc((size_t)BB*4*2*4);
  int*   fidx0  = (int*)  alloc((size_t)BB*512*4);
  float* coorq1 = (float*)alloc((size_t)BB*512*3*4);
  float* fq1    = (float*)alloc((size_t)BB*512*32*4);
  int*   idx2   = (int*)  alloc((size_t)BB*512*16*4);
  float* f2     = (float*)alloc((size_t)BB*512*64*4);
  int*   idx3   = (int*)  alloc((size_t)BB*512*16*4);
  float* f3     = (float*)alloc((size_t)BB*512*64*4);
  int*   fidx1  = (int*)  alloc((size_t)BB*128*4);
  float* fq2    = (float*)alloc((size_t)BB*128*64*4);
  int*   idx4   = (int*)  alloc((size_t)BB*128*16*4);

  // ---- union scratch region (48 MB): kNN partials alias the A/B edge-conv buffers.
  char* U = (char*)alloc((size_t)48<<20);
  float* pd         = (float*)U;                              // max 32 MiB
  unsigned char* pi = (unsigned char*)(U + ((size_t)34<<20)); // max 8 MiB
  float* A  = (float*)U;                                      // max 16 MiB
  float* Bq = (float*)(U + ((size_t)20<<20));                 // max 4 MiB

  auto cdiv = [](int a, int b){ return (a+b-1)/b; };

  // stage 0: projection
  proj_kernel<<<cdiv(BB*2048,256),256,0,stream>>>(x, w_in, b_in, f0);

  // ---- stage 1: 2048 q x 2048 k ----
  knn_part_kernel<<<dim3(BB,8,8),256,0,stream>>>(x, x, 2048, 2048, pd, pi);
  knn_merge_kernel<<<cdiv(BB*2048,256),256,0,stream>>>(pd, pi, 2048, 8, idx1);
  gemv_kernel<8,32,false><<<cdiv(BB*2048*4,256),256,0,stream>>>(f0, w1, A, 2048);
  gemv_kernel<8,32,true ><<<cdiv(BB*2048*4,256),256,0,stream>>>(f0, w1, Bq, 2048);
  stats_kernel<32><<<dim3(BB,4,8),256,0,stream>>>(A, Bq, idx1, 2048, 2048, part);
  statsred_kernel<<<1,128,0,stream>>>(part, 8, 8.0*2048*16, statsv);
  final_kernel<32><<<dim3(cdiv(2048*32,256),BB),256,0,stream>>>(A, Bq, idx1, statsv, g1, be1, f1, 2048, 2048);

  // ---- fps 2048 -> 512 + gather ----
  fps_kernel<8><<<BB,256,0,stream>>>(x, 512, fidx0);
  gather_kernel<32><<<cdiv(BB*512,256),256,0,stream>>>(fidx0, x, f1, coorq1, fq1, 2048, 512);

  // ---- stage 2: 512 q x 2048 k ----
  knn_part_kernel<<<dim3(BB,2,8),256,0,stream>>>(coorq1, x, 512, 2048, pd, pi);
  knn_merge_kernel<<<cdiv(BB*512,256),256,0,stream>>>(pd, pi, 512, 8, idx2);
  gemv_kernel<32,64,false><<<cdiv(BB*2048*8,256),256,0,stream>>>(f1, w2, A, 2048);
  gemv_kernel<32,64,true ><<<cdiv(BB*512*8,256),256,0,stream>>>(fq1, w2, Bq, 512);
  stats_kernel<64><<<dim3(BB,4,8),256,0,stream>>>(A, Bq, idx2, 512, 2048, part);
  statsred_kernel<<<1,128,0,stream>>>(part, 8, 16.0*512*16, statsv);
  final_kernel<64><<<dim3(cdiv(512*64,256),BB),256,0,stream>>>(A, Bq, idx2, statsv, g2, be2, f2, 512, 2048);

  // ---- stage 3: 512 q x 512 k ----
  knn_part_kernel<<<dim3(BB,2,2),256,0,stream>>>(coorq1, coorq1, 512, 512, pd, pi);
  knn_merge_kernel<<<cdiv(BB*512,256),256,0,stream>>>(pd, pi, 512, 2, idx3);
  gemv_kernel<64,64,false><<<cdiv(BB*512*8,256),256,0,stream>>>(f2, w3, A, 512);
  gemv_kernel<64,64,true ><<<cdiv(BB*512*8,256),256,0,stream>>>(f2, w3, Bq, 512);
  stats_kernel<64><<<dim3(BB,4,8),256,0,stream>>>(A, Bq, idx3, 512, 512, part);
  statsred_kernel<<<1,128,0,stream>>>(part, 8, 16.0*512*16, statsv);
  final_kernel<64><<<dim3(cdiv(512*64,256),BB),256,0,stream>>>(A, Bq, idx3, statsv, g3, be3, f3, 512, 512);

  // ---- fps 512 -> 128 + gather (coords straight into d_out) ----
  fps_kernel<2><<<BB,256,0,stream>>>(coorq1, 128, fidx1);
  gather_kernel<64><<<cdiv(BB*128,256),256,0,stream>>>(fidx1, coorq1, f3, coor_out, fq2, 512, 128);

  // ---- stage 4: 128 q x 512 k ----
  knn_part_kernel<<<dim3(BB,1,2),256,0,stream>>>(coor_out, coorq1, 128, 512, pd, pi);
  knn_merge_kernel<<<cdiv(BB*128,256),256,0,stream>>>(pd, pi, 128, 2, idx4);
  gemv_kernel<64,256,false><<<cdiv(BB*512*32,256),256,0,stream>>>(f3, w4, A, 512);
  gemv_kernel<64,256,true ><<<cdiv(BB*128*32,256),256,0,stream>>>(fq2, w4, Bq, 128);
  stats_kernel<256><<<dim3(BB,4,8),256,0,stream>>>(A, Bq, idx4, 128, 512, part);
  statsred_kernel<<<1,128,0,stream>>>(part, 8, 64.0*128*16, statsv);
  final_kernel<256><<<dim3(cdiv(128*256,256),BB),256,0,stream>>>(A, Bq, idx4, statsv, g4, be4, f_out, 128, 512);
}

// Round 6
// 1537.734 us; speedup vs baseline: 1.0618x; 1.0618x over previous
//
#include <hip/hip_runtime.h>

#define BB 32
#define NPTS0 2048
#define KNB 16
#define KC 256   // key-chunk size for two-pass kNN

constexpr int ilog2c(int n){ int l=0; while(n>1){ n>>=1; ++l; } return l; }

static __device__ __forceinline__ float sq3(float a, float b, float c){
  return __fadd_rn(__fadd_rn(__fmul_rn(a,a),__fmul_rn(b,b)),__fmul_rn(c,c));
}

// DPP helpers: templated so dpp_ctrl/row_mask are integer constant expressions.
// bound_ctrl=false -> invalid/masked lanes keep own value (idempotent for max/min).
template<int CTRL, int RM>
static __device__ __forceinline__ float dpp_maxf(float v){
  int s = __builtin_amdgcn_update_dpp(__float_as_int(v), __float_as_int(v), CTRL, RM, 0xF, false);
  return fmaxf(v, __int_as_float(s));
}
template<int CTRL, int RM>
static __device__ __forceinline__ unsigned dpp_minu(unsigned v){
  unsigned s = (unsigned)__builtin_amdgcn_update_dpp((int)v, (int)v, CTRL, RM, 0xF, false);
  return s < v ? s : v;
}

// ---------------- proj body: f0[b][n][o] = w_in(8x3) @ x + b_in ----------------
static __device__ __forceinline__ void proj_body(const float* __restrict__ x,
    const float* __restrict__ w, const float* __restrict__ bias, float* __restrict__ f0,
    int blk)
{
  int gid = blk*256 + threadIdx.x;
  if (gid >= BB*NPTS0) return;
  float x0 = x[gid*3+0], x1 = x[gid*3+1], x2 = x[gid*3+2];
  #pragma unroll
  for (int o = 0; o < 8; ++o){
    float acc = __fmul_rn(w[o*3+0], x0);
    acc = __fmaf_rn(w[o*3+1], x1, acc);
    acc = __fmaf_rn(w[o*3+2], x2, acc);
    f0[gid*8+o] = __fadd_rn(acc, bias[o]);
  }
}

// ---------------- kNN pass 1 body: per 256-key chunk, local top-16 ----------------
static __device__ __forceinline__ void knn_part_body(const float* __restrict__ qpts,
    const float* __restrict__ kpts, int Nq, int Nk, int nkc,
    float* __restrict__ pd, unsigned char* __restrict__ pi,
    int b, int qcb, int kc, float4* kk4)
{
  int tid = threadIdx.x;
  {
    int j = kc*KC + tid;                 // Nk is always a multiple of 256
    float a = kpts[(b*Nk+j)*3+0];
    float c = kpts[(b*Nk+j)*3+1];
    float d = kpts[(b*Nk+j)*3+2];
    kk4[tid] = make_float4(a, c, d, sq3(a,c,d));
  }
  __syncthreads();
  int q = qcb*256 + tid;
  if (q >= Nq) return;
  float qx = qpts[(b*Nq+q)*3+0], qy = qpts[(b*Nq+q)*3+1], qz = qpts[(b*Nq+q)*3+2];
  float qq = sq3(qx,qy,qz);
  float th[KNB]; int ti[KNB];
  #pragma unroll
  for (int i=0;i<KNB;i++){ th[i] = __builtin_inff(); ti[i] = 0; }
  for (int j=0;j<KC;j++){
    float4 k4 = kk4[j];
    float dot = __fmul_rn(qx,k4.x);
    dot = __fmaf_rn(qy,k4.y,dot);
    dot = __fmaf_rn(qz,k4.z,dot);
    float d = __fadd_rn(__fsub_rn(qq, __fmul_rn(2.0f,dot)), k4.w);
    if (d < th[KNB-1]){                   // strict <: equal dist keeps earlier index
      th[KNB-1] = d; ti[KNB-1] = j;
      #pragma unroll
      for (int i=KNB-1;i>0;--i){
        if (th[i] < th[i-1]){
          float tv=th[i]; th[i]=th[i-1]; th[i-1]=tv;
          int tj=ti[i]; ti[i]=ti[i-1]; ti[i-1]=tj;
        }
      }
    }
  }
  size_t base = ((size_t)(b*Nq+q)*nkc + kc)*KNB;
  #pragma unroll
  for (int i=0;i<KNB;i++){ pd[base+i] = th[i]; pi[base+i] = (unsigned char)ti[i]; }
}

// ---------------- FPS body: slim f32-max reduce + index equality match ------------
// Selection semantics identical to jnp.argmax over exact f32 distances:
// max value (fmaxf chain preserves bits), ties -> lowest global index
// (per-thread lowest-t match, then u32-min reduce, then ordered 4-way merge).
template<int NPT>   // points = NPT*256
static __device__ __forceinline__ void fps_body(const float* __restrict__ pts,
    int S, int* __restrict__ oidx, int b, float* swpraw)
{
  constexpr int N = NPT*256;
  float (*swp)[4][8] = reinterpret_cast<float(*)[4][8]>(swpraw);  // [2][4][8]
  int tid = threadIdx.x, wid = tid >> 6;
  const float* P = pts + (size_t)b*N*3;
  float c0x = P[0], c0y = P[1], c0z = P[2];
  float px[NPT], py[NPT], pz[NPT], dist[NPT];
  float bm = -1.0f;
  #pragma unroll
  for (int t=0;t<NPT;t++){
    int i = t*256 + tid;
    px[t] = P[i*3+0]; py[t] = P[i*3+1]; pz[t] = P[i*3+2];
    float dx = __fsub_rn(px[t], c0x);
    float dy = __fsub_rn(py[t], c0y);
    float dz = __fsub_rn(pz[t], c0z);
    dist[t] = sq3(dx,dy,dz);
    bm = fmaxf(bm, dist[t]);
  }
  if (tid == 0) oidx[b*S+0] = 0;
  for (int s=1; s<S; ++s){
    // ---- wave f32 max reduce -> lane 63 ----
    float v = bm;
    v = dpp_maxf<0x111, 0xF>(v);   // row_shr:1
    v = dpp_maxf<0x112, 0xF>(v);   // row_shr:2
    v = dpp_maxf<0x114, 0xF>(v);   // row_shr:4
    v = dpp_maxf<0x118, 0xF>(v);   // row_shr:8
    v = dpp_maxf<0x142, 0xA>(v);   // row_bcast:15 -> rows 1,3
    v = dpp_maxf<0x143, 0xC>(v);   // row_bcast:31 -> rows 2,3
    float m_w = __int_as_float(__builtin_amdgcn_readlane(__float_as_int(v), 63));
    // ---- candidate index: lowest local i with dist == wave max ----
    unsigned ci = 0xFFFFFFFFu;
    #pragma unroll
    for (int t=NPT-1; t>=0; --t)
      if (dist[t] == m_w) ci = (unsigned)(t*256 + tid);
    ci = dpp_minu<0x111, 0xF>(ci);
    ci = dpp_minu<0x112, 0xF>(ci);
    ci = dpp_minu<0x114, 0xF>(ci);
    ci = dpp_minu<0x118, 0xF>(ci);
    ci = dpp_minu<0x142, 0xA>(ci);
    ci = dpp_minu<0x143, 0xC>(ci);
    unsigned idx_w = (unsigned)__builtin_amdgcn_readlane((int)ci, 63);
    int par = s & 1;
    if (tid == (int)(idx_w & 255u)){       // owner lane carries the coords
      float cx = px[0], cy = py[0], cz = pz[0];
      #pragma unroll
      for (int t=1;t<NPT;t++)
        if ((idx_w>>8) == (unsigned)t){ cx = px[t]; cy = py[t]; cz = pz[t]; }
      float4* wp = (float4*)&swp[par][wid][0];
      *wp = make_float4(m_w, __uint_as_float(idx_w), cx, cy);
      swp[par][wid][4] = cz;
    }
    __syncthreads();                       // single barrier per iteration (parity dbuf)
    float4 q0 = *(const float4*)&swp[par][0][0]; float z0 = swp[par][0][4];
    float4 q1 = *(const float4*)&swp[par][1][0]; float z1 = swp[par][1][4];
    float4 q2 = *(const float4*)&swp[par][2][0]; float z2 = swp[par][2][4];
    float4 q3 = *(const float4*)&swp[par][3][0]; float z3 = swp[par][3][4];
    float mm = q0.x; unsigned mi = __float_as_uint(q0.y);
    float sx = q0.z, sy = q0.w, sz = z0;
    if (q1.x > mm || (q1.x == mm && __float_as_uint(q1.y) < mi)){
      mm = q1.x; mi = __float_as_uint(q1.y); sx = q1.z; sy = q1.w; sz = z1; }
    if (q2.x > mm || (q2.x == mm && __float_as_uint(q2.y) < mi)){
      mm = q2.x; mi = __float_as_uint(q2.y); sx = q2.z; sy = q2.w; sz = z2; }
    if (q3.x > mm || (q3.x == mm && __float_as_uint(q3.y) < mi)){
      mm = q3.x; mi = __float_as_uint(q3.y); sx = q3.z; sy = q3.w; sz = z3; }
    if (tid == 0) oidx[b*S+s] = (int)mi;
    // ---- fused distance update + next local max (pure VALU, 8 instr/pt) ----
    float nbm = -1.0f;
    #pragma unroll
    for (int t=0;t<NPT;t++){
      float dx = __fsub_rn(px[t], sx);
      float dy = __fsub_rn(py[t], sy);
      float dz = __fsub_rn(pz[t], sz);
      float nd = sq3(dx,dy,dz);
      float d = fminf(dist[t], nd);
      dist[t] = d;
      nbm = fmaxf(nbm, d);
    }
    bm = nbm;
  }
}

// ---------------- fused launch 1: fps0 (32) | knn1_part (2048) | proj (256) --------
__global__ __launch_bounds__(256) void fused1_kernel(const float* __restrict__ x,
    const float* __restrict__ w_in, const float* __restrict__ b_in,
    float* __restrict__ f0, float* __restrict__ pd1, unsigned char* __restrict__ pi1,
    int* __restrict__ fidx0)
{
  __shared__ __align__(16) char sm[4096];
  int bid = blockIdx.x;
  if (bid < 32){
    fps_body<8>(x, 512, fidx0, bid, (float*)sm);
  } else if (bid < 32+2048){
    int r = bid - 32;
    int b = r & 31; int rest = r >> 5;
    knn_part_body(x, x, 2048, 2048, 8, pd1, pi1, b, rest & 7, rest >> 3, (float4*)sm);
  } else {
    proj_body(x, w_in, b_in, f0, bid - 2080);
  }
}

// ---------------- fused launch 2: fps1 (32) | knn2_part (512) | knn3_part (128) ----
__global__ __launch_bounds__(256) void fused2_kernel(const float* __restrict__ coorq1,
    const float* __restrict__ x,
    float* __restrict__ pd2, unsigned char* __restrict__ pi2,
    float* __restrict__ pd3, unsigned char* __restrict__ pi3,
    int* __restrict__ fidx1)
{
  __shared__ __align__(16) char sm[4096];
  int bid = blockIdx.x;
  if (bid < 32){
    fps_body<2>(coorq1, 128, fidx1, bid, (float*)sm);
  } else if (bid < 32+512){
    int r = bid - 32;
    int b = r & 31; int rest = r >> 5;
    knn_part_body(coorq1, x, 512, 2048, 8, pd2, pi2, b, rest & 1, rest >> 1, (float4*)sm);
  } else {
    int r = bid - 544;
    int b = r & 31; int rest = r >> 5;
    knn_part_body(coorq1, coorq1, 512, 512, 2, pd3, pi3, b, rest & 1, rest >> 1, (float4*)sm);
  }
}

// ---------------- standalone knn_part (stage 4) ----------------
__global__ __launch_bounds__(256) void knn_part_kernel(const float* __restrict__ qpts,
    const float* __restrict__ kpts, int Nq, int Nk,
    float* __restrict__ pd, unsigned char* __restrict__ pi)
{
  __shared__ __align__(16) float4 kk4[KC];
  knn_part_body(qpts, kpts, Nq, Nk, gridDim.z, pd, pi,
                blockIdx.x, blockIdx.y, blockIdx.z, kk4);
}

// ---------------- kNN pass 2: merge per-chunk sorted candidate lists ----------------
__global__ __launch_bounds__(256) void knn_merge_kernel(const float* __restrict__ pd,
    const unsigned char* __restrict__ pi, int Nq, int nkc, int* __restrict__ oidx)
{
  int gid = blockIdx.x*256 + threadIdx.x;
  if (gid >= BB*Nq) return;               // gid = b*Nq + q
  float th[KNB]; int ti[KNB];
  #pragma unroll
  for (int i=0;i<KNB;i++){ th[i] = __builtin_inff(); ti[i] = 0; }
  size_t base = (size_t)gid*nkc*KNB;
  for (int kc=0;kc<nkc;kc++){
    size_t cb = base + (size_t)kc*KNB;
    for (int i=0;i<KNB;i++){
      float d = pd[cb+i];
      if (d >= th[KNB-1]) break;           // chunk list sorted ascending
      int j = kc*KC + (int)pi[cb+i];
      th[KNB-1] = d; ti[KNB-1] = j;
      #pragma unroll
      for (int m=KNB-1;m>0;--m){
        if (th[m] < th[m-1]){
          float tv=th[m]; th[m]=th[m-1]; th[m-1]=tv;
          int tj=ti[m]; ti[m]=ti[m-1]; ti[m-1]=tj;
        }
      }
    }
  }
  #pragma unroll
  for (int i=0;i<KNB;i++) oidx[gid*KNB + i] = ti[i];
}

// ---------------- per-point GEMV: out[pn][o] = sum_c M[o][c]*fin[pn][c] ----------------
template<int C, int O, bool DIFF>
__global__ __launch_bounds__(256) void gemv_kernel(const float* __restrict__ fin,
    const float* __restrict__ W, float* __restrict__ out, int Npts)
{
  constexpr int NT = O/8;
  constexpr int LNT = ilog2c(NT);
  int gid = blockIdx.x*256 + threadIdx.x;
  if (gid >= BB*Npts*NT) return;
  int tile = gid & (NT-1);
  int pn = gid >> LNT;
  const float* frow = fin + pn*C;
  float f[C];
  #pragma unroll
  for (int c=0;c<C;c++) f[c] = frow[c];
  float acc[8];
  const float* wbase = W + (tile*8)*(2*C);
  #pragma unroll
  for (int oo=0;oo<8;oo++){
    const float* wrow = wbase + oo*(2*C);
    float a = 0.f;
    #pragma unroll
    for (int c=0;c<C;c++){
      float wv = DIFF ? __fsub_rn(wrow[C+c], wrow[c]) : wrow[c];
      a = __fmaf_rn(wv, f[c], a);
    }
    acc[oo] = a;
  }
  float* orow = out + pn*O + tile*8;
  #pragma unroll
  for (int oo=0;oo<8;oo++) orow[oo] = acc[oo];
}

// ---------------- GN stats pass ----------------
template<int O>
__global__ __launch_bounds__(256) void stats_kernel(const float* __restrict__ A,
    const float* __restrict__ Bq, const int* __restrict__ idx, int Nq, int Nk,
    double* __restrict__ part)
{
  constexpr int O4 = O/4;
  constexpr int LO4 = ilog2c(O4);
  int b = blockIdx.x, g = blockIdx.y, split = blockIdx.z;
  int nsplit = gridDim.z;
  int qlen = Nq / nsplit;
  int q0 = split * qlen;
  int tid = threadIdx.x;
  int total = qlen * KNB * O4;
  double s1 = 0.0, s2 = 0.0;
  for (int s = tid; s < total; s += 256){
    int oin = s & (O4-1);
    int rest = s >> LO4;
    int kk = rest & (KNB-1);
    int q = q0 + (rest >> 4);
    int j = idx[(b*Nq+q)*KNB + kk];
    float y = A[(b*Nk+j)*O + g*O4 + oin] + Bq[(b*Nq+q)*O + g*O4 + oin];
    s1 += (double)y;
    s2 += (double)y * (double)y;
  }
  #pragma unroll
  for (int m=32;m>0;m>>=1){ s1 += __shfl_down(s1,m); s2 += __shfl_down(s2,m); }
  __shared__ double sh1[4], sh2[4];
  int lane = tid & 63, w = tid >> 6;
  if (lane == 0){ sh1[w]=s1; sh2[w]=s2; }
  __syncthreads();
  if (tid == 0){
    double t1 = (sh1[0]+sh1[1])+(sh1[2]+sh1[3]);
    double t2 = (sh2[0]+sh2[1])+(sh2[2]+sh2[3]);
    int pi = (b*4+g)*nsplit + split;
    part[pi*2] = t1; part[pi*2+1] = t2;
  }
}

__global__ __launch_bounds__(128) void statsred_kernel(const double* __restrict__ part,
    int nsplit, double cnt, float* __restrict__ stats)
{
  int t = threadIdx.x;
  if (t >= BB*4) return;
  double s1=0.0, s2=0.0;
  for (int i=0;i<nsplit;i++){ s1 += part[(t*nsplit+i)*2]; s2 += part[(t*nsplit+i)*2+1]; }
  double mean = s1/cnt;
  double var = s2/cnt - mean*mean;
  double rstd = 1.0 / sqrt(var + 1e-5);
  stats[t*2] = (float)mean;
  stats[t*2+1] = (float)rstd;
}

// ---------------- final pass: normalize, gamma/beta, leaky, max over 16 ------
template<int O>
__global__ __launch_bounds__(256) void final_kernel(const float* __restrict__ A,
    const float* __restrict__ Bq, const int* __restrict__ idx,
    const float* __restrict__ stats, const float* __restrict__ gamma,
    const float* __restrict__ beta, float* __restrict__ fout, int Nq, int Nk)
{
  constexpr int LO = ilog2c(O);
  constexpr int LO4 = ilog2c(O/4);
  int b = blockIdx.y;
  int t = blockIdx.x*256 + threadIdx.x;
  if (t >= Nq*O) return;
  int o = t & (O-1);
  int q = t >> LO;
  int g = o >> LO4;
  float mu   = stats[(b*4+g)*2];
  float rstd = stats[(b*4+g)*2+1];
  float gam = gamma[o], bet = beta[o];
  float bq = Bq[(b*Nq+q)*O + o];
  const int* ip = idx + (b*Nq+q)*KNB;
  float m = -__builtin_inff();
  #pragma unroll
  for (int kk=0;kk<KNB;kk++){
    int j = ip[kk];
    float y = A[(b*Nk+j)*O + o] + bq;
    float yn = __fmul_rn(__fsub_rn(y, mu), rstd);
    float yv = __fadd_rn(__fmul_rn(yn, gam), bet);
    float l = yv >= 0.f ? yv : 0.2f*yv;
    m = fmaxf(m, l);
  }
  fout[(b*Nq+q)*O + o] = m;
}

// ---------------- gathers --------------------------------
template<int C>
__global__ __launch_bounds__(256) void gather_kernel(const int* __restrict__ fidx,
    const float* __restrict__ pts, const float* __restrict__ fin,
    float* __restrict__ cq, float* __restrict__ fq, int Nin, int Nout)
{
  int gid = blockIdx.x*256 + threadIdx.x;
  if (gid >= BB*Nout) return;
  int b = gid / Nout;
  int i = gid - b*Nout;
  int src = fidx[b*Nout + i];
  #pragma unroll
  for (int c=0;c<3;c++) cq[gid*3+c] = pts[(b*Nin+src)*3+c];
  #pragma unroll
  for (int c=0;c<C;c++) fq[gid*C+c] = fin[(b*Nin+src)*C+c];
}

__global__ __launch_bounds__(256) void gatherc_kernel(const int* __restrict__ fidx,
    const float* __restrict__ pts, float* __restrict__ cq, int Nin, int Nout)
{
  int gid = blockIdx.x*256 + threadIdx.x;
  if (gid >= BB*Nout) return;
  int b = gid / Nout;
  int i = gid - b*Nout;
  int src = fidx[b*Nout + i];
  #pragma unroll
  for (int c=0;c<3;c++) cq[gid*3+c] = pts[(b*Nin+src)*3+c];
}

template<int C>
__global__ __launch_bounds__(256) void gatherf_kernel(const int* __restrict__ fidx,
    const float* __restrict__ fin, float* __restrict__ fq, int Nin, int Nout)
{
  int gid = blockIdx.x*256 + threadIdx.x;
  if (gid >= BB*Nout) return;
  int b = gid / Nout;
  int i = gid - b*Nout;
  int src = fidx[b*Nout + i];
  #pragma unroll
  for (int c=0;c<C;c++) fq[gid*C+c] = fin[(b*Nin+src)*C+c];
}

extern "C" void kernel_launch(void* const* d_in, const int* in_sizes, int n_in,
                              void* d_out, int out_size, void* d_ws, size_t ws_size,
                              hipStream_t stream)
{
  (void)in_sizes; (void)n_in; (void)out_size; (void)ws_size;
  const float* x    = (const float*)d_in[0];
  const float* w_in = (const float*)d_in[1];
  const float* b_in = (const float*)d_in[2];
  const float* w1 = (const float*)d_in[3];
  const float* g1 = (const float*)d_in[4];
  const float* be1= (const float*)d_in[5];
  const float* w2 = (const float*)d_in[6];
  const float* g2 = (const float*)d_in[7];
  const float* be2= (const float*)d_in[8];
  const float* w3 = (const float*)d_in[9];
  const float* g3 = (const float*)d_in[10];
  const float* be3= (const float*)d_in[11];
  const float* w4 = (const float*)d_in[12];
  const float* g4 = (const float*)d_in[13];
  const float* be4= (const float*)d_in[14];

  float* out = (float*)d_out;
  float* coor_out = out;                    // (32,128,3)
  float* f_out = out + BB*128*3;            // (32,128,256)

  char* ws = (char*)d_ws;
  size_t off = 0;
  auto alloc = [&](size_t bytes)->void*{ void* p = ws + off; off += (bytes + 255) & ~(size_t)255; return p; };

  // ---- persistent buffers (~41.5 MB) ----
  float* f0     = (float*)alloc((size_t)BB*2048*8*4);
  int*   idx1   = (int*)  alloc((size_t)BB*2048*16*4);
  float* f1     = (float*)alloc((size_t)BB*2048*32*4);
  double* part  = (double*)alloc((size_t)BB*4*8*2*8);
  float* statsv = (float*)alloc((size_t)BB*4*2*4);
  int*   fidx0  = (int*)  alloc((size_t)BB*512*4);
  float* coorq1 = (float*)alloc((size_t)BB*512*3*4);
  float* fq1    = (float*)alloc((size_t)BB*512*32*4);
  int*   idx2   = (int*)  alloc((size_t)BB*512*16*4);
  float* f2     = (float*)alloc((size_t)BB*512*64*4);
  int*   idx3   = (int*)  alloc((size_t)BB*512*16*4);
  float* f3     = (float*)alloc((size_t)BB*512*64*4);
  int*   fidx1  = (int*)  alloc((size_t)BB*128*4);
  float* fq2    = (float*)alloc((size_t)BB*128*64*4);
  int*   idx4   = (int*)  alloc((size_t)BB*128*16*4);
  // stage 2/3/4 kNN partials (persistent so they can coexist with fused launches)
  float* pd2          = (float*)alloc((size_t)BB*512*8*KNB*4);   // 8 MB
  unsigned char* pi2  = (unsigned char*)alloc((size_t)BB*512*8*KNB); // 2 MB
  float* pd3          = (float*)alloc((size_t)BB*512*2*KNB*4);   // 2 MB
  unsigned char* pi3  = (unsigned char*)alloc((size_t)BB*512*2*KNB); // 0.5 MB
  float* pd4          = (float*)alloc((size_t)BB*128*2*KNB*4);   // 0.5 MB
  unsigned char* pi4  = (unsigned char*)alloc((size_t)BB*128*2*KNB); // 0.125 MB

  // ---- union scratch region (48 MB): stage-1 kNN partials alias A/B buffers.
  char* U = (char*)alloc((size_t)48<<20);
  float* pd1         = (float*)U;                              // 32 MiB
  unsigned char* pi1 = (unsigned char*)(U + ((size_t)34<<20)); // 8 MiB
  float* A  = (float*)U;                                       // max 16 MiB
  float* Bq = (float*)(U + ((size_t)20<<20));                  // max 4 MiB

  auto cdiv = [](int a, int b){ return (a+b-1)/b; };

  // ==== F1: fps0 | knn1_part | proj (all depend only on x) ====
  fused1_kernel<<<2336,256,0,stream>>>(x, w_in, b_in, f0, pd1, pi1, fidx0);

  // ---- stage 1 compute ----
  knn_merge_kernel<<<cdiv(BB*2048,256),256,0,stream>>>(pd1, pi1, 2048, 8, idx1);
  gemv_kernel<8,32,false><<<cdiv(BB*2048*4,256),256,0,stream>>>(f0, w1, A, 2048);
  gemv_kernel<8,32,true ><<<cdiv(BB*2048*4,256),256,0,stream>>>(f0, w1, Bq, 2048);
  stats_kernel<32><<<dim3(BB,4,8),256,0,stream>>>(A, Bq, idx1, 2048, 2048, part);
  statsred_kernel<<<1,128,0,stream>>>(part, 8, 8.0*2048*16, statsv);
  final_kernel<32><<<dim3(cdiv(2048*32,256),BB),256,0,stream>>>(A, Bq, idx1, statsv, g1, be1, f1, 2048, 2048);

  // ---- gather at fps0 indices ----
  gather_kernel<32><<<cdiv(BB*512,256),256,0,stream>>>(fidx0, x, f1, coorq1, fq1, 2048, 512);

  // ==== F2: fps1 | knn2_part | knn3_part (all depend only on coorq1/x) ====
  fused2_kernel<<<672,256,0,stream>>>(coorq1, x, pd2, pi2, pd3, pi3, fidx1);

  knn_merge_kernel<<<cdiv(BB*512,256),256,0,stream>>>(pd2, pi2, 512, 8, idx2);
  knn_merge_kernel<<<cdiv(BB*512,256),256,0,stream>>>(pd3, pi3, 512, 2, idx3);

  // ---- stage-4 kNN early (needs only fidx1 + coorq1) ----
  gatherc_kernel<<<cdiv(BB*128,256),256,0,stream>>>(fidx1, coorq1, coor_out, 512, 128);
  knn_part_kernel<<<dim3(BB,1,2),256,0,stream>>>(coor_out, coorq1, 128, 512, pd4, pi4);
  knn_merge_kernel<<<cdiv(BB*128,256),256,0,stream>>>(pd4, pi4, 128, 2, idx4);

  // ---- stage 2 compute ----
  gemv_kernel<32,64,false><<<cdiv(BB*2048*8,256),256,0,stream>>>(f1, w2, A, 2048);
  gemv_kernel<32,64,true ><<<cdiv(BB*512*8,256),256,0,stream>>>(fq1, w2, Bq, 512);
  stats_kernel<64><<<dim3(BB,4,8),256,0,stream>>>(A, Bq, idx2, 512, 2048, part);
  statsred_kernel<<<1,128,0,stream>>>(part, 8, 16.0*512*16, statsv);
  final_kernel<64><<<dim3(cdiv(512*64,256),BB),256,0,stream>>>(A, Bq, idx2, statsv, g2, be2, f2, 512, 2048);

  // ---- stage 3 compute ----
  gemv_kernel<64,64,false><<<cdiv(BB*512*8,256),256,0,stream>>>(f2, w3, A, 512);
  gemv_kernel<64,64,true ><<<cdiv(BB*512*8,256),256,0,stream>>>(f2, w3, Bq, 512);
  stats_kernel<64><<<dim3(BB,4,8),256,0,stream>>>(A, Bq, idx3, 512, 512, part);
  statsred_kernel<<<1,128,0,stream>>>(part, 8, 16.0*512*16, statsv);
  final_kernel<64><<<dim3(cdiv(512*64,256),BB),256,0,stream>>>(A, Bq, idx3, statsv, g3, be3, f3, 512, 512);

  // ---- stage 4 compute ----
  gatherf_kernel<64><<<cdiv(BB*128,256),256,0,stream>>>(fidx1, f3, fq2, 512, 128);
  gemv_kernel<64,256,false><<<cdiv(BB*512*32,256),256,0,stream>>>(f3, w4, A, 512);
  gemv_kernel<64,256,true ><<<cdiv(BB*128*32,256),256,0,stream>>>(fq2, w4, Bq, 128);
  stats_kernel<256><<<dim3(BB,4,8),256,0,stream>>>(A, Bq, idx4, 128, 512, part);
  statsred_kernel<<<1,128,0,stream>>>(part, 8, 64.0*128*16, statsv);
  final_kernel<256><<<dim3(cdiv(128*256,256),BB),256,0,stream>>>(A, Bq, idx4, statsv, g4, be4, f_out, 128, 512);
}

// Round 7
// 1536.066 us; speedup vs baseline: 1.0630x; 1.0011x over previous
//
#include <hip/hip_runtime.h>

#define BB 32
#define NPTS0 2048
#define KNB 16
#define KC 256   // key-chunk size for two-pass kNN

constexpr int ilog2c(int n){ int l=0; while(n>1){ n>>=1; ++l; } return l; }

static __device__ __forceinline__ float sq3(float a, float b, float c){
  return __fadd_rn(__fadd_rn(__fmul_rn(a,a),__fmul_rn(b,b)),__fmul_rn(c,c));
}

// DPP helpers: templated so dpp_ctrl/row_mask are integer constant expressions.
// bound_ctrl=false -> invalid/masked lanes keep own value (idempotent for max/min).
template<int CTRL, int RM>
static __device__ __forceinline__ float dpp_maxf(float v){
  int s = __builtin_amdgcn_update_dpp(__float_as_int(v), __float_as_int(v), CTRL, RM, 0xF, false);
  return fmaxf(v, __int_as_float(s));
}
template<int CTRL, int RM>
static __device__ __forceinline__ unsigned dpp_minu(unsigned v){
  unsigned s = (unsigned)__builtin_amdgcn_update_dpp((int)v, (int)v, CTRL, RM, 0xF, false);
  return s < v ? s : v;
}

// ---------------- proj body: f0[b][n][o] = w_in(8x3) @ x + b_in ----------------
static __device__ __forceinline__ void proj_body(const float* __restrict__ x,
    const float* __restrict__ w, const float* __restrict__ bias, float* __restrict__ f0,
    int blk)
{
  int gid = blk*256 + threadIdx.x;
  if (gid >= BB*NPTS0) return;
  float x0 = x[gid*3+0], x1 = x[gid*3+1], x2 = x[gid*3+2];
  #pragma unroll
  for (int o = 0; o < 8; ++o){
    float acc = __fmul_rn(w[o*3+0], x0);
    acc = __fmaf_rn(w[o*3+1], x1, acc);
    acc = __fmaf_rn(w[o*3+2], x2, acc);
    f0[gid*8+o] = __fadd_rn(acc, bias[o]);
  }
}

// ---------------- kNN pass 1 body: per 256-key chunk, local top-16 ----------------
static __device__ __forceinline__ void knn_part_body(const float* __restrict__ qpts,
    const float* __restrict__ kpts, int Nq, int Nk, int nkc,
    float* __restrict__ pd, unsigned char* __restrict__ pi,
    int b, int qcb, int kc, float4* kk4)
{
  int tid = threadIdx.x;
  {
    int j = kc*KC + tid;                 // Nk is always a multiple of 256
    float a = kpts[(b*Nk+j)*3+0];
    float c = kpts[(b*Nk+j)*3+1];
    float d = kpts[(b*Nk+j)*3+2];
    kk4[tid] = make_float4(a, c, d, sq3(a,c,d));
  }
  __syncthreads();
  int q = qcb*256 + tid;
  if (q >= Nq) return;
  float qx = qpts[(b*Nq+q)*3+0], qy = qpts[(b*Nq+q)*3+1], qz = qpts[(b*Nq+q)*3+2];
  float qq = sq3(qx,qy,qz);
  float th[KNB]; int ti[KNB];
  #pragma unroll
  for (int i=0;i<KNB;i++){ th[i] = __builtin_inff(); ti[i] = 0; }
  for (int j=0;j<KC;j++){
    float4 k4 = kk4[j];
    float dot = __fmul_rn(qx,k4.x);
    dot = __fmaf_rn(qy,k4.y,dot);
    dot = __fmaf_rn(qz,k4.z,dot);
    float d = __fadd_rn(__fsub_rn(qq, __fmul_rn(2.0f,dot)), k4.w);
    if (d < th[KNB-1]){                   // strict <: equal dist keeps earlier index
      th[KNB-1] = d; ti[KNB-1] = j;
      #pragma unroll
      for (int i=KNB-1;i>0;--i){
        if (th[i] < th[i-1]){
          float tv=th[i]; th[i]=th[i-1]; th[i-1]=tv;
          int tj=ti[i]; ti[i]=ti[i-1]; ti[i-1]=tj;
        }
      }
    }
  }
  size_t base = ((size_t)(b*Nq+q)*nkc + kc)*KNB;
  #pragma unroll
  for (int i=0;i<KNB;i++){ pd[base+i] = th[i]; pi[base+i] = (unsigned char)ti[i]; }
}

// ---------------- FPS body: slim f32-max reduce + index equality match ------------
// Selection semantics identical to jnp.argmax over exact f32 distances:
// max value (fmaxf chain preserves bits), ties -> lowest global index
// (per-thread lowest-t match, then u32-min reduce, then ordered 4-way merge).
template<int NPT>   // points = NPT*256
static __device__ __forceinline__ void fps_body(const float* __restrict__ pts,
    int S, int* __restrict__ oidx, int b, float* swpraw)
{
  constexpr int N = NPT*256;
  float (*swp)[4][8] = reinterpret_cast<float(*)[4][8]>(swpraw);  // [2][4][8]
  int tid = threadIdx.x, wid = tid >> 6;
  const float* P = pts + (size_t)b*N*3;
  float c0x = P[0], c0y = P[1], c0z = P[2];
  float px[NPT], py[NPT], pz[NPT], dist[NPT];
  float bm = -1.0f;
  #pragma unroll
  for (int t=0;t<NPT;t++){
    int i = t*256 + tid;
    px[t] = P[i*3+0]; py[t] = P[i*3+1]; pz[t] = P[i*3+2];
    float dx = __fsub_rn(px[t], c0x);
    float dy = __fsub_rn(py[t], c0y);
    float dz = __fsub_rn(pz[t], c0z);
    dist[t] = sq3(dx,dy,dz);
    bm = fmaxf(bm, dist[t]);
  }
  if (tid == 0) oidx[b*S+0] = 0;
  for (int s=1; s<S; ++s){
    // ---- wave f32 max reduce -> lane 63 ----
    float v = bm;
    v = dpp_maxf<0x111, 0xF>(v);   // row_shr:1
    v = dpp_maxf<0x112, 0xF>(v);   // row_shr:2
    v = dpp_maxf<0x114, 0xF>(v);   // row_shr:4
    v = dpp_maxf<0x118, 0xF>(v);   // row_shr:8
    v = dpp_maxf<0x142, 0xA>(v);   // row_bcast:15 -> rows 1,3
    v = dpp_maxf<0x143, 0xC>(v);   // row_bcast:31 -> rows 2,3
    float m_w = __int_as_float(__builtin_amdgcn_readlane(__float_as_int(v), 63));
    // ---- candidate index: lowest local i with dist == wave max ----
    unsigned ci = 0xFFFFFFFFu;
    #pragma unroll
    for (int t=NPT-1; t>=0; --t)
      if (dist[t] == m_w) ci = (unsigned)(t*256 + tid);
    ci = dpp_minu<0x111, 0xF>(ci);
    ci = dpp_minu<0x112, 0xF>(ci);
    ci = dpp_minu<0x114, 0xF>(ci);
    ci = dpp_minu<0x118, 0xF>(ci);
    ci = dpp_minu<0x142, 0xA>(ci);
    ci = dpp_minu<0x143, 0xC>(ci);
    unsigned idx_w = (unsigned)__builtin_amdgcn_readlane((int)ci, 63);
    int par = s & 1;
    if (tid == (int)(idx_w & 255u)){       // each wave's winner lane writes its slot
      float cx = px[0], cy = py[0], cz = pz[0];
      #pragma unroll
      for (int t=1;t<NPT;t++)
        if ((idx_w>>8) == (unsigned)t){ cx = px[t]; cy = py[t]; cz = pz[t]; }
      float4* wp = (float4*)&swp[par][wid][0];
      *wp = make_float4(m_w, __uint_as_float(idx_w), cx, cy);
      swp[par][wid][4] = cz;
    }
    __syncthreads();                       // single barrier per iteration (parity dbuf)
    float4 q0 = *(const float4*)&swp[par][0][0]; float z0 = swp[par][0][4];
    float4 q1 = *(const float4*)&swp[par][1][0]; float z1 = swp[par][1][4];
    float4 q2 = *(const float4*)&swp[par][2][0]; float z2 = swp[par][2][4];
    float4 q3 = *(const float4*)&swp[par][3][0]; float z3 = swp[par][3][4];
    float mm = q0.x; unsigned mi = __float_as_uint(q0.y);
    float sx = q0.z, sy = q0.w, sz = z0;
    if (q1.x > mm || (q1.x == mm && __float_as_uint(q1.y) < mi)){
      mm = q1.x; mi = __float_as_uint(q1.y); sx = q1.z; sy = q1.w; sz = z1; }
    if (q2.x > mm || (q2.x == mm && __float_as_uint(q2.y) < mi)){
      mm = q2.x; mi = __float_as_uint(q2.y); sx = q2.z; sy = q2.w; sz = z2; }
    if (q3.x > mm || (q3.x == mm && __float_as_uint(q3.y) < mi)){
      mm = q3.x; mi = __float_as_uint(q3.y); sx = q3.z; sy = q3.w; sz = z3; }
    if (tid == 0) oidx[b*S+s] = (int)mi;
    // ---- fused distance update + next local max (pure VALU, 8 instr/pt) ----
    float nbm = -1.0f;
    #pragma unroll
    for (int t=0;t<NPT;t++){
      float dx = __fsub_rn(px[t], sx);
      float dy = __fsub_rn(py[t], sy);
      float dz = __fsub_rn(pz[t], sz);
      float nd = sq3(dx,dy,dz);
      float d = fminf(dist[t], nd);
      dist[t] = d;
      nbm = fmaxf(nbm, d);
    }
    bm = nbm;
  }
}

// ---------------- fused launch 1: fps0 (32) | knn1_part (2048) | proj (256) --------
// __launch_bounds__(256,1): min 1 wave/EU -> full VGPR budget; prevents the
// allocator from demoting per-thread arrays (th/ti/px/dist) to scratch (R6:
// VGPR_Count=24 => scratch-resident arrays => 5x slowdown).
__global__ __launch_bounds__(256, 1) void fused1_kernel(const float* __restrict__ x,
    const float* __restrict__ w_in, const float* __restrict__ b_in,
    float* __restrict__ f0, float* __restrict__ pd1, unsigned char* __restrict__ pi1,
    int* __restrict__ fidx0)
{
  __shared__ __align__(16) char sm[4096];
  int bid = blockIdx.x;
  if (bid < 32){
    fps_body<8>(x, 512, fidx0, bid, (float*)sm);
  } else if (bid < 32+2048){
    int r = bid - 32;
    int b = r & 31; int rest = r >> 5;
    knn_part_body(x, x, 2048, 2048, 8, pd1, pi1, b, rest & 7, rest >> 3, (float4*)sm);
  } else {
    proj_body(x, w_in, b_in, f0, bid - 2080);
  }
}

// ---------------- fused launch 2: fps1 (32) | knn2_part (512) | knn3_part (128) ----
__global__ __launch_bounds__(256, 1) void fused2_kernel(const float* __restrict__ coorq1,
    const float* __restrict__ x,
    float* __restrict__ pd2, unsigned char* __restrict__ pi2,
    float* __restrict__ pd3, unsigned char* __restrict__ pi3,
    int* __restrict__ fidx1)
{
  __shared__ __align__(16) char sm[4096];
  int bid = blockIdx.x;
  if (bid < 32){
    fps_body<2>(coorq1, 128, fidx1, bid, (float*)sm);
  } else if (bid < 32+512){
    int r = bid - 32;
    int b = r & 31; int rest = r >> 5;
    knn_part_body(coorq1, x, 512, 2048, 8, pd2, pi2, b, rest & 1, rest >> 1, (float4*)sm);
  } else {
    int r = bid - 544;
    int b = r & 31; int rest = r >> 5;
    knn_part_body(coorq1, coorq1, 512, 512, 2, pd3, pi3, b, rest & 1, rest >> 1, (float4*)sm);
  }
}

// ---------------- standalone knn_part (stage 4) ----------------
__global__ __launch_bounds__(256) void knn_part_kernel(const float* __restrict__ qpts,
    const float* __restrict__ kpts, int Nq, int Nk,
    float* __restrict__ pd, unsigned char* __restrict__ pi)
{
  __shared__ __align__(16) float4 kk4[KC];
  knn_part_body(qpts, kpts, Nq, Nk, gridDim.z, pd, pi,
                blockIdx.x, blockIdx.y, blockIdx.z, kk4);
}

// ---------------- kNN pass 2: merge per-chunk sorted candidate lists ----------------
__global__ __launch_bounds__(256) void knn_merge_kernel(const float* __restrict__ pd,
    const unsigned char* __restrict__ pi, int Nq, int nkc, int* __restrict__ oidx)
{
  int gid = blockIdx.x*256 + threadIdx.x;
  if (gid >= BB*Nq) return;               // gid = b*Nq + q
  float th[KNB]; int ti[KNB];
  #pragma unroll
  for (int i=0;i<KNB;i++){ th[i] = __builtin_inff(); ti[i] = 0; }
  size_t base = (size_t)gid*nkc*KNB;
  for (int kc=0;kc<nkc;kc++){
    size_t cb = base + (size_t)kc*KNB;
    for (int i=0;i<KNB;i++){
      float d = pd[cb+i];
      if (d >= th[KNB-1]) break;           // chunk list sorted ascending
      int j = kc*KC + (int)pi[cb+i];
      th[KNB-1] = d; ti[KNB-1] = j;
      #pragma unroll
      for (int m=KNB-1;m>0;--m){
        if (th[m] < th[m-1]){
          float tv=th[m]; th[m]=th[m-1]; th[m-1]=tv;
          int tj=ti[m]; ti[m]=ti[m-1]; ti[m-1]=tj;
        }
      }
    }
  }
  #pragma unroll
  for (int i=0;i<KNB;i++) oidx[gid*KNB + i] = ti[i];
}

// ---------------- per-point GEMV: out[pn][o] = sum_c M[o][c]*fin[pn][c] ----------------
template<int C, int O, bool DIFF>
__global__ __launch_bounds__(256) void gemv_kernel(const float* __restrict__ fin,
    const float* __restrict__ W, float* __restrict__ out, int Npts)
{
  constexpr int NT = O/8;
  constexpr int LNT = ilog2c(NT);
  int gid = blockIdx.x*256 + threadIdx.x;
  if (gid >= BB*Npts*NT) return;
  int tile = gid & (NT-1);
  int pn = gid >> LNT;
  const float* frow = fin + pn*C;
  float f[C];
  #pragma unroll
  for (int c=0;c<C;c++) f[c] = frow[c];
  float acc[8];
  const float* wbase = W + (tile*8)*(2*C);
  #pragma unroll
  for (int oo=0;oo<8;oo++){
    const float* wrow = wbase + oo*(2*C);
    float a = 0.f;
    #pragma unroll
    for (int c=0;c<C;c++){
      float wv = DIFF ? __fsub_rn(wrow[C+c], wrow[c]) : wrow[c];
      a = __fmaf_rn(wv, f[c], a);
    }
    acc[oo] = a;
  }
  float* orow = out + pn*O + tile*8;
  #pragma unroll
  for (int oo=0;oo<8;oo++) orow[oo] = acc[oo];
}

// ---------------- GN stats pass ----------------
template<int O>
__global__ __launch_bounds__(256) void stats_kernel(const float* __restrict__ A,
    const float* __restrict__ Bq, const int* __restrict__ idx, int Nq, int Nk,
    double* __restrict__ part)
{
  constexpr int O4 = O/4;
  constexpr int LO4 = ilog2c(O4);
  int b = blockIdx.x, g = blockIdx.y, split = blockIdx.z;
  int nsplit = gridDim.z;
  int qlen = Nq / nsplit;
  int q0 = split * qlen;
  int tid = threadIdx.x;
  int total = qlen * KNB * O4;
  double s1 = 0.0, s2 = 0.0;
  for (int s = tid; s < total; s += 256){
    int oin = s & (O4-1);
    int rest = s >> LO4;
    int kk = rest & (KNB-1);
    int q = q0 + (rest >> 4);
    int j = idx[(b*Nq+q)*KNB + kk];
    float y = A[(b*Nk+j)*O + g*O4 + oin] + Bq[(b*Nq+q)*O + g*O4 + oin];
    s1 += (double)y;
    s2 += (double)y * (double)y;
  }
  #pragma unroll
  for (int m=32;m>0;m>>=1){ s1 += __shfl_down(s1,m); s2 += __shfl_down(s2,m); }
  __shared__ double sh1[4], sh2[4];
  int lane = tid & 63, w = tid >> 6;
  if (lane == 0){ sh1[w]=s1; sh2[w]=s2; }
  __syncthreads();
  if (tid == 0){
    double t1 = (sh1[0]+sh1[1])+(sh1[2]+sh1[3]);
    double t2 = (sh2[0]+sh2[1])+(sh2[2]+sh2[3]);
    int pi = (b*4+g)*nsplit + split;
    part[pi*2] = t1; part[pi*2+1] = t2;
  }
}

__global__ __launch_bounds__(128) void statsred_kernel(const double* __restrict__ part,
    int nsplit, double cnt, float* __restrict__ stats)
{
  int t = threadIdx.x;
  if (t >= BB*4) return;
  double s1=0.0, s2=0.0;
  for (int i=0;i<nsplit;i++){ s1 += part[(t*nsplit+i)*2]; s2 += part[(t*nsplit+i)*2+1]; }
  double mean = s1/cnt;
  double var = s2/cnt - mean*mean;
  double rstd = 1.0 / sqrt(var + 1e-5);
  stats[t*2] = (float)mean;
  stats[t*2+1] = (float)rstd;
}

// ---------------- final pass: normalize, gamma/beta, leaky, max over 16 ------
template<int O>
__global__ __launch_bounds__(256) void final_kernel(const float* __restrict__ A,
    const float* __restrict__ Bq, const int* __restrict__ idx,
    const float* __restrict__ stats, const float* __restrict__ gamma,
    const float* __restrict__ beta, float* __restrict__ fout, int Nq, int Nk)
{
  constexpr int LO = ilog2c(O);
  constexpr int LO4 = ilog2c(O/4);
  int b = blockIdx.y;
  int t = blockIdx.x*256 + threadIdx.x;
  if (t >= Nq*O) return;
  int o = t & (O-1);
  int q = t >> LO;
  int g = o >> LO4;
  float mu   = stats[(b*4+g)*2];
  float rstd = stats[(b*4+g)*2+1];
  float gam = gamma[o], bet = beta[o];
  float bq = Bq[(b*Nq+q)*O + o];
  const int* ip = idx + (b*Nq+q)*KNB;
  float m = -__builtin_inff();
  #pragma unroll
  for (int kk=0;kk<KNB;kk++){
    int j = ip[kk];
    float y = A[(b*Nk+j)*O + o] + bq;
    float yn = __fmul_rn(__fsub_rn(y, mu), rstd);
    float yv = __fadd_rn(__fmul_rn(yn, gam), bet);
    float l = yv >= 0.f ? yv : 0.2f*yv;
    m = fmaxf(m, l);
  }
  fout[(b*Nq+q)*O + o] = m;
}

// ---------------- gathers --------------------------------
template<int C>
__global__ __launch_bounds__(256) void gather_kernel(const int* __restrict__ fidx,
    const float* __restrict__ pts, const float* __restrict__ fin,
    float* __restrict__ cq, float* __restrict__ fq, int Nin, int Nout)
{
  int gid = blockIdx.x*256 + threadIdx.x;
  if (gid >= BB*Nout) return;
  int b = gid / Nout;
  int i = gid - b*Nout;
  int src = fidx[b*Nout + i];
  #pragma unroll
  for (int c=0;c<3;c++) cq[gid*3+c] = pts[(b*Nin+src)*3+c];
  #pragma unroll
  for (int c=0;c<C;c++) fq[gid*C+c] = fin[(b*Nin+src)*C+c];
}

__global__ __launch_bounds__(256) void gatherc_kernel(const int* __restrict__ fidx,
    const float* __restrict__ pts, float* __restrict__ cq, int Nin, int Nout)
{
  int gid = blockIdx.x*256 + threadIdx.x;
  if (gid >= BB*Nout) return;
  int b = gid / Nout;
  int i = gid - b*Nout;
  int src = fidx[b*Nout + i];
  #pragma unroll
  for (int c=0;c<3;c++) cq[gid*3+c] = pts[(b*Nin+src)*3+c];
}

template<int C>
__global__ __launch_bounds__(256) void gatherf_kernel(const int* __restrict__ fidx,
    const float* __restrict__ fin, float* __restrict__ fq, int Nin, int Nout)
{
  int gid = blockIdx.x*256 + threadIdx.x;
  if (gid >= BB*Nout) return;
  int b = gid / Nout;
  int i = gid - b*Nout;
  int src = fidx[b*Nout + i];
  #pragma unroll
  for (int c=0;c<C;c++) fq[gid*C+c] = fin[(b*Nin+src)*C+c];
}

extern "C" void kernel_launch(void* const* d_in, const int* in_sizes, int n_in,
                              void* d_out, int out_size, void* d_ws, size_t ws_size,
                              hipStream_t stream)
{
  (void)in_sizes; (void)n_in; (void)out_size; (void)ws_size;
  const float* x    = (const float*)d_in[0];
  const float* w_in = (const float*)d_in[1];
  const float* b_in = (const float*)d_in[2];
  const float* w1 = (const float*)d_in[3];
  const float* g1 = (const float*)d_in[4];
  const float* be1= (const float*)d_in[5];
  const float* w2 = (const float*)d_in[6];
  const float* g2 = (const float*)d_in[7];
  const float* be2= (const float*)d_in[8];
  const float* w3 = (const float*)d_in[9];
  const float* g3 = (const float*)d_in[10];
  const float* be3= (const float*)d_in[11];
  const float* w4 = (const float*)d_in[12];
  const float* g4 = (const float*)d_in[13];
  const float* be4= (const float*)d_in[14];

  float* out = (float*)d_out;
  float* coor_out = out;                    // (32,128,3)
  float* f_out = out + BB*128*3;            // (32,128,256)

  char* ws = (char*)d_ws;
  size_t off = 0;
  auto alloc = [&](size_t bytes)->void*{ void* p = ws + off; off += (bytes + 255) & ~(size_t)255; return p; };

  // ---- persistent buffers (~41.5 MB) ----
  float* f0     = (float*)alloc((size_t)BB*2048*8*4);
  int*   idx1   = (int*)  alloc((size_t)BB*2048*16*4);
  float* f1     = (float*)alloc((size_t)BB*2048*32*4);
  double* part  = (double*)alloc((size_t)BB*4*8*2*8);
  float* statsv = (float*)alloc((size_t)BB*4*2*4);
  int*   fidx0  = (int*)  alloc((size_t)BB*512*4);
  float* coorq1 = (float*)alloc((size_t)BB*512*3*4);
  float* fq1    = (float*)alloc((size_t)BB*512*32*4);
  int*   idx2   = (int*)  alloc((size_t)BB*512*16*4);
  float* f2     = (float*)alloc((size_t)BB*512*64*4);
  int*   idx3   = (int*)  alloc((size_t)BB*512*16*4);
  float* f3     = (float*)alloc((size_t)BB*512*64*4);
  int*   fidx1  = (int*)  alloc((size_t)BB*128*4);
  float* fq2    = (float*)alloc((size_t)BB*128*64*4);
  int*   idx4   = (int*)  alloc((size_t)BB*128*16*4);
  // stage 2/3/4 kNN partials (persistent so they can coexist with fused launches)
  float* pd2          = (float*)alloc((size_t)BB*512*8*KNB*4);   // 8 MB
  unsigned char* pi2  = (unsigned char*)alloc((size_t)BB*512*8*KNB); // 2 MB
  float* pd3          = (float*)alloc((size_t)BB*512*2*KNB*4);   // 2 MB
  unsigned char* pi3  = (unsigned char*)alloc((size_t)BB*512*2*KNB); // 0.5 MB
  float* pd4          = (float*)alloc((size_t)BB*128*2*KNB*4);   // 0.5 MB
  unsigned char* pi4  = (unsigned char*)alloc((size_t)BB*128*2*KNB); // 0.125 MB

  // ---- union scratch region (48 MB): stage-1 kNN partials alias A/B buffers.
  char* U = (char*)alloc((size_t)48<<20);
  float* pd1         = (float*)U;                              // 32 MiB
  unsigned char* pi1 = (unsigned char*)(U + ((size_t)34<<20)); // 8 MiB
  float* A  = (float*)U;                                       // max 16 MiB
  float* Bq = (float*)(U + ((size_t)20<<20));                  // max 4 MiB

  auto cdiv = [](int a, int b){ return (a+b-1)/b; };

  // ==== F1: fps0 | knn1_part | proj (all depend only on x) ====
  fused1_kernel<<<2336,256,0,stream>>>(x, w_in, b_in, f0, pd1, pi1, fidx0);

  // ---- stage 1 compute ----
  knn_merge_kernel<<<cdiv(BB*2048,256),256,0,stream>>>(pd1, pi1, 2048, 8, idx1);
  gemv_kernel<8,32,false><<<cdiv(BB*2048*4,256),256,0,stream>>>(f0, w1, A, 2048);
  gemv_kernel<8,32,true ><<<cdiv(BB*2048*4,256),256,0,stream>>>(f0, w1, Bq, 2048);
  stats_kernel<32><<<dim3(BB,4,8),256,0,stream>>>(A, Bq, idx1, 2048, 2048, part);
  statsred_kernel<<<1,128,0,stream>>>(part, 8, 8.0*2048*16, statsv);
  final_kernel<32><<<dim3(cdiv(2048*32,256),BB),256,0,stream>>>(A, Bq, idx1, statsv, g1, be1, f1, 2048, 2048);

  // ---- gather at fps0 indices ----
  gather_kernel<32><<<cdiv(BB*512,256),256,0,stream>>>(fidx0, x, f1, coorq1, fq1, 2048, 512);

  // ==== F2: fps1 | knn2_part | knn3_part (all depend only on coorq1/x) ====
  fused2_kernel<<<672,256,0,stream>>>(coorq1, x, pd2, pi2, pd3, pi3, fidx1);

  knn_merge_kernel<<<cdiv(BB*512,256),256,0,stream>>>(pd2, pi2, 512, 8, idx2);
  knn_merge_kernel<<<cdiv(BB*512,256),256,0,stream>>>(pd3, pi3, 512, 2, idx3);

  // ---- stage-4 kNN early (needs only fidx1 + coorq1) ----
  gatherc_kernel<<<cdiv(BB*128,256),256,0,stream>>>(fidx1, coorq1, coor_out, 512, 128);
  knn_part_kernel<<<dim3(BB,1,2),256,0,stream>>>(coor_out, coorq1, 128, 512, pd4, pi4);
  knn_merge_kernel<<<cdiv(BB*128,256),256,0,stream>>>(pd4, pi4, 128, 2, idx4);

  // ---- stage 2 compute ----
  gemv_kernel<32,64,false><<<cdiv(BB*2048*8,256),256,0,stream>>>(f1, w2, A, 2048);
  gemv_kernel<32,64,true ><<<cdiv(BB*512*8,256),256,0,stream>>>(fq1, w2, Bq, 512);
  stats_kernel<64><<<dim3(BB,4,8),256,0,stream>>>(A, Bq, idx2, 512, 2048, part);
  statsred_kernel<<<1,128,0,stream>>>(part, 8, 16.0*512*16, statsv);
  final_kernel<64><<<dim3(cdiv(512*64,256),BB),256,0,stream>>>(A, Bq, idx2, statsv, g2, be2, f2, 512, 2048);

  // ---- stage 3 compute ----
  gemv_kernel<64,64,false><<<cdiv(BB*512*8,256),256,0,stream>>>(f2, w3, A, 512);
  gemv_kernel<64,64,true ><<<cdiv(BB*512*8,256),256,0,stream>>>(f2, w3, Bq, 512);
  stats_kernel<64><<<dim3(BB,4,8),256,0,stream>>>(A, Bq, idx3, 512, 512, part);
  statsred_kernel<<<1,128,0,stream>>>(part, 8, 16.0*512*16, statsv);
  final_kernel<64><<<dim3(cdiv(512*64,256),BB),256,0,stream>>>(A, Bq, idx3, statsv, g3, be3, f3, 512, 512);

  // ---- stage 4 compute ----
  gatherf_kernel<64><<<cdiv(BB*128,256),256,0,stream>>>(fidx1, f3, fq2, 512, 128);
  gemv_kernel<64,256,false><<<cdiv(BB*512*32,256),256,0,stream>>>(f3, w4, A, 512);
  gemv_kernel<64,256,true ><<<cdiv(BB*128*32,256),256,0,stream>>>(fq2, w4, Bq, 128);
  stats_kernel<256><<<dim3(BB,4,8),256,0,stream>>>(A, Bq, idx4, 128, 512, part);
  statsred_kernel<<<1,128,0,stream>>>(part, 8, 64.0*128*16, statsv);
  final_kernel<256><<<dim3(cdiv(128*256,256),BB),256,0,stream>>>(A, Bq, idx4, statsv, g4, be4, f_out, 128, 512);
}

// Round 8
// 1438.050 us; speedup vs baseline: 1.1355x; 1.0682x over previous
//
#include <hip/hip_runtime.h>

#define BB 32
#define NPTS0 2048
#define KNB 16
#define KC 256   // key-chunk size for two-pass kNN

constexpr int ilog2c(int n){ int l=0; while(n>1){ n>>=1; ++l; } return l; }

static __device__ __forceinline__ float sq3(float a, float b, float c){
  return __fadd_rn(__fadd_rn(__fmul_rn(a,a),__fmul_rn(b,b)),__fmul_rn(c,c));
}

// DPP helpers: templated so dpp_ctrl/row_mask are integer constant expressions.
template<int CTRL, int RM>
static __device__ __forceinline__ float dpp_maxf(float v){
  int s = __builtin_amdgcn_update_dpp(__float_as_int(v), __float_as_int(v), CTRL, RM, 0xF, false);
  return fmaxf(v, __int_as_float(s));
}
template<int CTRL, int RM>
static __device__ __forceinline__ unsigned dpp_minu(unsigned v){
  unsigned s = (unsigned)__builtin_amdgcn_update_dpp((int)v, (int)v, CTRL, RM, 0xF, false);
  return s < v ? s : v;
}

// ---------------- proj body ----------------
static __device__ __forceinline__ void proj_body(const float* __restrict__ x,
    const float* __restrict__ w, const float* __restrict__ bias, float* __restrict__ f0,
    int blk)
{
  int gid = blk*256 + threadIdx.x;
  if (gid >= BB*NPTS0) return;
  float x0 = x[gid*3+0], x1 = x[gid*3+1], x2 = x[gid*3+2];
  #pragma unroll
  for (int o = 0; o < 8; ++o){
    float acc = __fmul_rn(w[o*3+0], x0);
    acc = __fmaf_rn(w[o*3+1], x1, acc);
    acc = __fmaf_rn(w[o*3+2], x2, acc);
    f0[gid*8+o] = __fadd_rn(acc, bias[o]);
  }
}

// ---------------- kNN pass 1 body: NAMED-SCALAR top-16 (no allocas -> registers) ------
// Same algorithm/compare order as array version: strict-< insert at slot15, bubble down.
#define KDECL(I) float th##I = __builtin_inff(); int ti##I = 0;
#define KINS(I,J) if (th##I < th##J){ float tv=th##I; th##I=th##J; th##J=tv; \
                                      int tj=ti##I; ti##I=ti##J; ti##J=tj; }
#define KST(I) pd[base+I] = th##I; pi[base+I] = (unsigned char)ti##I;

static __device__ __forceinline__ void knn_part_body(const float* __restrict__ qpts,
    const float* __restrict__ kpts, int Nq, int Nk, int nkc,
    float* __restrict__ pd, unsigned char* __restrict__ pi,
    int b, int qcb, int kc, float4* kk4)
{
  int tid = threadIdx.x;
  {
    int j = kc*KC + tid;                 // Nk is always a multiple of 256
    float a = kpts[(b*Nk+j)*3+0];
    float c = kpts[(b*Nk+j)*3+1];
    float d = kpts[(b*Nk+j)*3+2];
    kk4[tid] = make_float4(a, c, d, sq3(a,c,d));
  }
  __syncthreads();
  int q = qcb*256 + tid;
  if (q >= Nq) return;
  float qx = qpts[(b*Nq+q)*3+0], qy = qpts[(b*Nq+q)*3+1], qz = qpts[(b*Nq+q)*3+2];
  float qq = sq3(qx,qy,qz);
  KDECL(0) KDECL(1) KDECL(2) KDECL(3) KDECL(4) KDECL(5) KDECL(6) KDECL(7)
  KDECL(8) KDECL(9) KDECL(10) KDECL(11) KDECL(12) KDECL(13) KDECL(14) KDECL(15)
  for (int j=0;j<KC;j++){
    float4 k4 = kk4[j];
    float dot = __fmul_rn(qx,k4.x);
    dot = __fmaf_rn(qy,k4.y,dot);
    dot = __fmaf_rn(qz,k4.z,dot);
    float d = __fadd_rn(__fsub_rn(qq, __fmul_rn(2.0f,dot)), k4.w);
    if (d < th15){                        // strict <: equal dist keeps earlier index
      th15 = d; ti15 = j;
      KINS(15,14) KINS(14,13) KINS(13,12) KINS(12,11) KINS(11,10) KINS(10,9)
      KINS(9,8) KINS(8,7) KINS(7,6) KINS(6,5) KINS(5,4) KINS(4,3) KINS(3,2)
      KINS(2,1) KINS(1,0)
    }
  }
  size_t base = ((size_t)(b*Nq+q)*nkc + kc)*KNB;
  KST(0) KST(1) KST(2) KST(3) KST(4) KST(5) KST(6) KST(7)
  KST(8) KST(9) KST(10) KST(11) KST(12) KST(13) KST(14) KST(15)
}

// ---------------- FPS bodies: NAMED-SCALAR points/distances ----------------
// Selection semantics identical to jnp.argmax over exact f32 distances:
// max value (fmaxf chain preserves bits), ties -> lowest global index
// (descending-order match keeps lowest t, then u32-min reduce, ordered 4-way merge).
#define FPS_LOAD(T) float px##T, py##T, pz##T, d##T; { int i_=T*256+tid; \
  px##T=P[i_*3+0]; py##T=P[i_*3+1]; pz##T=P[i_*3+2]; \
  float dx_=__fsub_rn(px##T,c0x), dy_=__fsub_rn(py##T,c0y), dz_=__fsub_rn(pz##T,c0z); \
  d##T=sq3(dx_,dy_,dz_); bm=fmaxf(bm,d##T); }
#define FPS_MATCH(T) if (d##T == m_w) ci = (unsigned)(T*256 + tid);
#define FPS_OWN(T) if ((idx_w>>8) == T##u){ cx=px##T; cy=py##T; cz=pz##T; }
#define FPS_UPD(T) { float dx_=__fsub_rn(px##T,sx), dy_=__fsub_rn(py##T,sy), dz_=__fsub_rn(pz##T,sz); \
  float nd_=sq3(dx_,dy_,dz_); d##T=fminf(d##T,nd_); nbm=fmaxf(nbm,d##T); }

#define FPS_REDUCE_AND_PICK \
    float v = bm; \
    v = dpp_maxf<0x111, 0xF>(v); \
    v = dpp_maxf<0x112, 0xF>(v); \
    v = dpp_maxf<0x114, 0xF>(v); \
    v = dpp_maxf<0x118, 0xF>(v); \
    v = dpp_maxf<0x142, 0xA>(v); \
    v = dpp_maxf<0x143, 0xC>(v); \
    float m_w = __int_as_float(__builtin_amdgcn_readlane(__float_as_int(v), 63)); \
    unsigned ci = 0xFFFFFFFFu;

#define FPS_MIN_AND_MERGE \
    ci = dpp_minu<0x111, 0xF>(ci); \
    ci = dpp_minu<0x112, 0xF>(ci); \
    ci = dpp_minu<0x114, 0xF>(ci); \
    ci = dpp_minu<0x118, 0xF>(ci); \
    ci = dpp_minu<0x142, 0xA>(ci); \
    ci = dpp_minu<0x143, 0xC>(ci); \
    unsigned idx_w = (unsigned)__builtin_amdgcn_readlane((int)ci, 63); \
    int par = s & 1;

#define FPS_CROSSWAVE \
    __syncthreads(); \
    float4 q0 = *(const float4*)&swp[par][0][0]; float z0 = swp[par][0][4]; \
    float4 q1 = *(const float4*)&swp[par][1][0]; float z1 = swp[par][1][4]; \
    float4 q2 = *(const float4*)&swp[par][2][0]; float z2 = swp[par][2][4]; \
    float4 q3 = *(const float4*)&swp[par][3][0]; float z3 = swp[par][3][4]; \
    float mm = q0.x; unsigned mi = __float_as_uint(q0.y); \
    float sx = q0.z, sy = q0.w, sz = z0; \
    if (q1.x > mm || (q1.x == mm && __float_as_uint(q1.y) < mi)){ \
      mm = q1.x; mi = __float_as_uint(q1.y); sx = q1.z; sy = q1.w; sz = z1; } \
    if (q2.x > mm || (q2.x == mm && __float_as_uint(q2.y) < mi)){ \
      mm = q2.x; mi = __float_as_uint(q2.y); sx = q2.z; sy = q2.w; sz = z2; } \
    if (q3.x > mm || (q3.x == mm && __float_as_uint(q3.y) < mi)){ \
      mm = q3.x; mi = __float_as_uint(q3.y); sx = q3.z; sy = q3.w; sz = z3; } \
    if (tid == 0) oidx[b*S+s] = (int)mi;

static __device__ __forceinline__ void fps8_body(const float* __restrict__ pts,
    int S, int* __restrict__ oidx, int b, float* swpraw)
{
  float (*swp)[4][8] = reinterpret_cast<float(*)[4][8]>(swpraw);  // [2][4][8]
  int tid = threadIdx.x, wid = tid >> 6;
  const float* P = pts + (size_t)b*2048*3;
  float c0x = P[0], c0y = P[1], c0z = P[2];
  float bm = -1.0f;
  FPS_LOAD(0) FPS_LOAD(1) FPS_LOAD(2) FPS_LOAD(3)
  FPS_LOAD(4) FPS_LOAD(5) FPS_LOAD(6) FPS_LOAD(7)
  if (tid == 0) oidx[b*S+0] = 0;
  for (int s=1; s<S; ++s){
    FPS_REDUCE_AND_PICK
    FPS_MATCH(7) FPS_MATCH(6) FPS_MATCH(5) FPS_MATCH(4)
    FPS_MATCH(3) FPS_MATCH(2) FPS_MATCH(1) FPS_MATCH(0)
    FPS_MIN_AND_MERGE
    if (tid == (int)(idx_w & 255u)){       // each wave's winner lane writes its slot
      float cx = px0, cy = py0, cz = pz0;
      FPS_OWN(1) FPS_OWN(2) FPS_OWN(3) FPS_OWN(4) FPS_OWN(5) FPS_OWN(6) FPS_OWN(7)
      float4* wp = (float4*)&swp[par][wid][0];
      *wp = make_float4(m_w, __uint_as_float(idx_w), cx, cy);
      swp[par][wid][4] = cz;
    }
    FPS_CROSSWAVE
    float nbm = -1.0f;
    FPS_UPD(0) FPS_UPD(1) FPS_UPD(2) FPS_UPD(3)
    FPS_UPD(4) FPS_UPD(5) FPS_UPD(6) FPS_UPD(7)
    bm = nbm;
  }
}

static __device__ __forceinline__ void fps2_body(const float* __restrict__ pts,
    int S, int* __restrict__ oidx, int b, float* swpraw)
{
  float (*swp)[4][8] = reinterpret_cast<float(*)[4][8]>(swpraw);  // [2][4][8]
  int tid = threadIdx.x, wid = tid >> 6;
  const float* P = pts + (size_t)b*512*3;
  float c0x = P[0], c0y = P[1], c0z = P[2];
  float bm = -1.0f;
  FPS_LOAD(0) FPS_LOAD(1)
  if (tid == 0) oidx[b*S+0] = 0;
  for (int s=1; s<S; ++s){
    FPS_REDUCE_AND_PICK
    FPS_MATCH(1) FPS_MATCH(0)
    FPS_MIN_AND_MERGE
    if (tid == (int)(idx_w & 255u)){
      float cx = px0, cy = py0, cz = pz0;
      FPS_OWN(1)
      float4* wp = (float4*)&swp[par][wid][0];
      *wp = make_float4(m_w, __uint_as_float(idx_w), cx, cy);
      swp[par][wid][4] = cz;
    }
    FPS_CROSSWAVE
    float nbm = -1.0f;
    FPS_UPD(0) FPS_UPD(1)
    bm = nbm;
  }
}

// ---------------- fused launch 1: fps0 (32) | knn1_part (2048) | proj (256) --------
__global__ __launch_bounds__(256) void fused1_kernel(const float* __restrict__ x,
    const float* __restrict__ w_in, const float* __restrict__ b_in,
    float* __restrict__ f0, float* __restrict__ pd1, unsigned char* __restrict__ pi1,
    int* __restrict__ fidx0)
{
  __shared__ __align__(16) char sm[4096];
  int bid = blockIdx.x;
  if (bid < 32){
    fps8_body(x, 512, fidx0, bid, (float*)sm);
  } else if (bid < 32+2048){
    int r = bid - 32;
    int b = r & 31; int rest = r >> 5;
    knn_part_body(x, x, 2048, 2048, 8, pd1, pi1, b, rest & 7, rest >> 3, (float4*)sm);
  } else {
    proj_body(x, w_in, b_in, f0, bid - 2080);
  }
}

// ---------------- fused launch 2: fps1 (32) | knn2_part (512) | knn3_part (128) ----
__global__ __launch_bounds__(256) void fused2_kernel(const float* __restrict__ coorq1,
    const float* __restrict__ x,
    float* __restrict__ pd2, unsigned char* __restrict__ pi2,
    float* __restrict__ pd3, unsigned char* __restrict__ pi3,
    int* __restrict__ fidx1)
{
  __shared__ __align__(16) char sm[4096];
  int bid = blockIdx.x;
  if (bid < 32){
    fps2_body(coorq1, 128, fidx1, bid, (float*)sm);
  } else if (bid < 32+512){
    int r = bid - 32;
    int b = r & 31; int rest = r >> 5;
    knn_part_body(coorq1, x, 512, 2048, 8, pd2, pi2, b, rest & 1, rest >> 1, (float4*)sm);
  } else {
    int r = bid - 544;
    int b = r & 31; int rest = r >> 5;
    knn_part_body(coorq1, coorq1, 512, 512, 2, pd3, pi3, b, rest & 1, rest >> 1, (float4*)sm);
  }
}

// ---------------- standalone knn_part (stage 4) ----------------
__global__ __launch_bounds__(256) void knn_part_kernel(const float* __restrict__ qpts,
    const float* __restrict__ kpts, int Nq, int Nk,
    float* __restrict__ pd, unsigned char* __restrict__ pi)
{
  __shared__ __align__(16) float4 kk4[KC];
  knn_part_body(qpts, kpts, Nq, Nk, gridDim.z, pd, pi,
                blockIdx.x, blockIdx.y, blockIdx.z, kk4);
}

// ---------------- kNN pass 2: merge per-chunk sorted candidate lists ----------------
__global__ __launch_bounds__(256) void knn_merge_kernel(const float* __restrict__ pd,
    const unsigned char* __restrict__ pi, int Nq, int nkc, int* __restrict__ oidx)
{
  int gid = blockIdx.x*256 + threadIdx.x;
  if (gid >= BB*Nq) return;               // gid = b*Nq + q
  float th[KNB]; int ti[KNB];
  #pragma unroll
  for (int i=0;i<KNB;i++){ th[i] = __builtin_inff(); ti[i] = 0; }
  size_t base = (size_t)gid*nkc*KNB;
  for (int kc=0;kc<nkc;kc++){
    size_t cb = base + (size_t)kc*KNB;
    for (int i=0;i<KNB;i++){
      float d = pd[cb+i];
      if (d >= th[KNB-1]) break;           // chunk list sorted ascending
      int j = kc*KC + (int)pi[cb+i];
      th[KNB-1] = d; ti[KNB-1] = j;
      #pragma unroll
      for (int m=KNB-1;m>0;--m){
        if (th[m] < th[m-1]){
          float tv=th[m]; th[m]=th[m-1]; th[m-1]=tv;
          int tj=ti[m]; ti[m]=ti[m-1]; ti[m-1]=tj;
        }
      }
    }
  }
  #pragma unroll
  for (int i=0;i<KNB;i++) oidx[gid*KNB + i] = ti[i];
}

// ---------------- per-point GEMV ----------------
template<int C, int O, bool DIFF>
__global__ __launch_bounds__(256) void gemv_kernel(const float* __restrict__ fin,
    const float* __restrict__ W, float* __restrict__ out, int Npts)
{
  constexpr int NT = O/8;
  constexpr int LNT = ilog2c(NT);
  int gid = blockIdx.x*256 + threadIdx.x;
  if (gid >= BB*Npts*NT) return;
  int tile = gid & (NT-1);
  int pn = gid >> LNT;
  const float* frow = fin + pn*C;
  float f[C];
  #pragma unroll
  for (int c=0;c<C;c++) f[c] = frow[c];
  float acc[8];
  const float* wbase = W + (tile*8)*(2*C);
  #pragma unroll
  for (int oo=0;oo<8;oo++){
    const float* wrow = wbase + oo*(2*C);
    float a = 0.f;
    #pragma unroll
    for (int c=0;c<C;c++){
      float wv = DIFF ? __fsub_rn(wrow[C+c], wrow[c]) : wrow[c];
      a = __fmaf_rn(wv, f[c], a);
    }
    acc[oo] = a;
  }
  float* orow = out + pn*O + tile*8;
  #pragma unroll
  for (int oo=0;oo<8;oo++) orow[oo] = acc[oo];
}

// ---------------- GN stats pass ----------------
template<int O>
__global__ __launch_bounds__(256) void stats_kernel(const float* __restrict__ A,
    const float* __restrict__ Bq, const int* __restrict__ idx, int Nq, int Nk,
    double* __restrict__ part)
{
  constexpr int O4 = O/4;
  constexpr int LO4 = ilog2c(O4);
  int b = blockIdx.x, g = blockIdx.y, split = blockIdx.z;
  int nsplit = gridDim.z;
  int qlen = Nq / nsplit;
  int q0 = split * qlen;
  int tid = threadIdx.x;
  int total = qlen * KNB * O4;
  double s1 = 0.0, s2 = 0.0;
  for (int s = tid; s < total; s += 256){
    int oin = s & (O4-1);
    int rest = s >> LO4;
    int kk = rest & (KNB-1);
    int q = q0 + (rest >> 4);
    int j = idx[(b*Nq+q)*KNB + kk];
    float y = A[(b*Nk+j)*O + g*O4 + oin] + Bq[(b*Nq+q)*O + g*O4 + oin];
    s1 += (double)y;
    s2 += (double)y * (double)y;
  }
  #pragma unroll
  for (int m=32;m>0;m>>=1){ s1 += __shfl_down(s1,m); s2 += __shfl_down(s2,m); }
  __shared__ double sh1[4], sh2[4];
  int lane = tid & 63, w = tid >> 6;
  if (lane == 0){ sh1[w]=s1; sh2[w]=s2; }
  __syncthreads();
  if (tid == 0){
    double t1 = (sh1[0]+sh1[1])+(sh1[2]+sh1[3]);
    double t2 = (sh2[0]+sh2[1])+(sh2[2]+sh2[3]);
    int pi = (b*4+g)*nsplit + split;
    part[pi*2] = t1; part[pi*2+1] = t2;
  }
}

__global__ __launch_bounds__(128) void statsred_kernel(const double* __restrict__ part,
    int nsplit, double cnt, float* __restrict__ stats)
{
  int t = threadIdx.x;
  if (t >= BB*4) return;
  double s1=0.0, s2=0.0;
  for (int i=0;i<nsplit;i++){ s1 += part[(t*nsplit+i)*2]; s2 += part[(t*nsplit+i)*2+1]; }
  double mean = s1/cnt;
  double var = s2/cnt - mean*mean;
  double rstd = 1.0 / sqrt(var + 1e-5);
  stats[t*2] = (float)mean;
  stats[t*2+1] = (float)rstd;
}

// ---------------- final pass ----------------
template<int O>
__global__ __launch_bounds__(256) void final_kernel(const float* __restrict__ A,
    const float* __restrict__ Bq, const int* __restrict__ idx,
    const float* __restrict__ stats, const float* __restrict__ gamma,
    const float* __restrict__ beta, float* __restrict__ fout, int Nq, int Nk)
{
  constexpr int LO = ilog2c(O);
  constexpr int LO4 = ilog2c(O/4);
  int b = blockIdx.y;
  int t = blockIdx.x*256 + threadIdx.x;
  if (t >= Nq*O) return;
  int o = t & (O-1);
  int q = t >> LO;
  int g = o >> LO4;
  float mu   = stats[(b*4+g)*2];
  float rstd = stats[(b*4+g)*2+1];
  float gam = gamma[o], bet = beta[o];
  float bq = Bq[(b*Nq+q)*O + o];
  const int* ip = idx + (b*Nq+q)*KNB;
  float m = -__builtin_inff();
  #pragma unroll
  for (int kk=0;kk<KNB;kk++){
    int j = ip[kk];
    float y = A[(b*Nk+j)*O + o] + bq;
    float yn = __fmul_rn(__fsub_rn(y, mu), rstd);
    float yv = __fadd_rn(__fmul_rn(yn, gam), bet);
    float l = yv >= 0.f ? yv : 0.2f*yv;
    m = fmaxf(m, l);
  }
  fout[(b*Nq+q)*O + o] = m;
}

// ---------------- gathers --------------------------------
template<int C>
__global__ __launch_bounds__(256) void gather_kernel(const int* __restrict__ fidx,
    const float* __restrict__ pts, const float* __restrict__ fin,
    float* __restrict__ cq, float* __restrict__ fq, int Nin, int Nout)
{
  int gid = blockIdx.x*256 + threadIdx.x;
  if (gid >= BB*Nout) return;
  int b = gid / Nout;
  int i = gid - b*Nout;
  int src = fidx[b*Nout + i];
  #pragma unroll
  for (int c=0;c<3;c++) cq[gid*3+c] = pts[(b*Nin+src)*3+c];
  #pragma unroll
  for (int c=0;c<C;c++) fq[gid*C+c] = fin[(b*Nin+src)*C+c];
}

__global__ __launch_bounds__(256) void gatherc_kernel(const int* __restrict__ fidx,
    const float* __restrict__ pts, float* __restrict__ cq, int Nin, int Nout)
{
  int gid = blockIdx.x*256 + threadIdx.x;
  if (gid >= BB*Nout) return;
  int b = gid / Nout;
  int i = gid - b*Nout;
  int src = fidx[b*Nout + i];
  #pragma unroll
  for (int c=0;c<3;c++) cq[gid*3+c] = pts[(b*Nin+src)*3+c];
}

template<int C>
__global__ __launch_bounds__(256) void gatherf_kernel(const int* __restrict__ fidx,
    const float* __restrict__ fin, float* __restrict__ fq, int Nin, int Nout)
{
  int gid = blockIdx.x*256 + threadIdx.x;
  if (gid >= BB*Nout) return;
  int b = gid / Nout;
  int i = gid - b*Nout;
  int src = fidx[b*Nout + i];
  #pragma unroll
  for (int c=0;c<C;c++) fq[gid*C+c] = fin[(b*Nin+src)*C+c];
}

extern "C" void kernel_launch(void* const* d_in, const int* in_sizes, int n_in,
                              void* d_out, int out_size, void* d_ws, size_t ws_size,
                              hipStream_t stream)
{
  (void)in_sizes; (void)n_in; (void)out_size; (void)ws_size;
  const float* x    = (const float*)d_in[0];
  const float* w_in = (const float*)d_in[1];
  const float* b_in = (const float*)d_in[2];
  const float* w1 = (const float*)d_in[3];
  const float* g1 = (const float*)d_in[4];
  const float* be1= (const float*)d_in[5];
  const float* w2 = (const float*)d_in[6];
  const float* g2 = (const float*)d_in[7];
  const float* be2= (const float*)d_in[8];
  const float* w3 = (const float*)d_in[9];
  const float* g3 = (const float*)d_in[10];
  const float* be3= (const float*)d_in[11];
  const float* w4 = (const float*)d_in[12];
  const float* g4 = (const float*)d_in[13];
  const float* be4= (const float*)d_in[14];

  float* out = (float*)d_out;
  float* coor_out = out;                    // (32,128,3)
  float* f_out = out + BB*128*3;            // (32,128,256)

  char* ws = (char*)d_ws;
  size_t off = 0;
  auto alloc = [&](size_t bytes)->void*{ void* p = ws + off; off += (bytes + 255) & ~(size_t)255; return p; };

  // ---- persistent buffers (~41.5 MB) ----
  float* f0     = (float*)alloc((size_t)BB*2048*8*4);
  int*   idx1   = (int*)  alloc((size_t)BB*2048*16*4);
  float* f1     = (float*)alloc((size_t)BB*2048*32*4);
  double* part  = (double*)alloc((size_t)BB*4*8*2*8);
  float* statsv = (float*)alloc((size_t)BB*4*2*4);
  int*   fidx0  = (int*)  alloc((size_t)BB*512*4);
  float* coorq1 = (float*)alloc((size_t)BB*512*3*4);
  float* fq1    = (float*)alloc((size_t)BB*512*32*4);
  int*   idx2   = (int*)  alloc((size_t)BB*512*16*4);
  float* f2     = (float*)alloc((size_t)BB*512*64*4);
  int*   idx3   = (int*)  alloc((size_t)BB*512*16*4);
  float* f3     = (float*)alloc((size_t)BB*512*64*4);
  int*   fidx1  = (int*)  alloc((size_t)BB*128*4);
  float* fq2    = (float*)alloc((size_t)BB*128*64*4);
  int*   idx4   = (int*)  alloc((size_t)BB*128*16*4);
  // stage 2/3/4 kNN partials (persistent so they can coexist with fused launches)
  float* pd2          = (float*)alloc((size_t)BB*512*8*KNB*4);   // 8 MB
  unsigned char* pi2  = (unsigned char*)alloc((size_t)BB*512*8*KNB); // 2 MB
  float* pd3          = (float*)alloc((size_t)BB*512*2*KNB*4);   // 2 MB
  unsigned char* pi3  = (unsigned char*)alloc((size_t)BB*512*2*KNB); // 0.5 MB
  float* pd4          = (float*)alloc((size_t)BB*128*2*KNB*4);   // 0.5 MB
  unsigned char* pi4  = (unsigned char*)alloc((size_t)BB*128*2*KNB); // 0.125 MB

  // ---- union scratch region (48 MB): stage-1 kNN partials alias A/B buffers.
  char* U = (char*)alloc((size_t)48<<20);
  float* pd1         = (float*)U;                              // 32 MiB
  unsigned char* pi1 = (unsigned char*)(U + ((size_t)34<<20)); // 8 MiB
  float* A  = (float*)U;                                       // max 16 MiB
  float* Bq = (float*)(U + ((size_t)20<<20));                  // max 4 MiB

  auto cdiv = [](int a, int b){ return (a+b-1)/b; };

  // ==== F1: fps0 | knn1_part | proj (all depend only on x) ====
  fused1_kernel<<<2336,256,0,stream>>>(x, w_in, b_in, f0, pd1, pi1, fidx0);

  // ---- stage 1 compute ----
  knn_merge_kernel<<<cdiv(BB*2048,256),256,0,stream>>>(pd1, pi1, 2048, 8, idx1);
  gemv_kernel<8,32,false><<<cdiv(BB*2048*4,256),256,0,stream>>>(f0, w1, A, 2048);
  gemv_kernel<8,32,true ><<<cdiv(BB*2048*4,256),256,0,stream>>>(f0, w1, Bq, 2048);
  stats_kernel<32><<<dim3(BB,4,8),256,0,stream>>>(A, Bq, idx1, 2048, 2048, part);
  statsred_kernel<<<1,128,0,stream>>>(part, 8, 8.0*2048*16, statsv);
  final_kernel<32><<<dim3(cdiv(2048*32,256),BB),256,0,stream>>>(A, Bq, idx1, statsv, g1, be1, f1, 2048, 2048);

  // ---- gather at fps0 indices ----
  gather_kernel<32><<<cdiv(BB*512,256),256,0,stream>>>(fidx0, x, f1, coorq1, fq1, 2048, 512);

  // ==== F2: fps1 | knn2_part | knn3_part (all depend only on coorq1/x) ====
  fused2_kernel<<<672,256,0,stream>>>(coorq1, x, pd2, pi2, pd3, pi3, fidx1);

  knn_merge_kernel<<<cdiv(BB*512,256),256,0,stream>>>(pd2, pi2, 512, 8, idx2);
  knn_merge_kernel<<<cdiv(BB*512,256),256,0,stream>>>(pd3, pi3, 512, 2, idx3);

  // ---- stage-4 kNN early (needs only fidx1 + coorq1) ----
  gatherc_kernel<<<cdiv(BB*128,256),256,0,stream>>>(fidx1, coorq1, coor_out, 512, 128);
  knn_part_kernel<<<dim3(BB,1,2),256,0,stream>>>(coor_out, coorq1, 128, 512, pd4, pi4);
  knn_merge_kernel<<<cdiv(BB*128,256),256,0,stream>>>(pd4, pi4, 128, 2, idx4);

  // ---- stage 2 compute ----
  gemv_kernel<32,64,false><<<cdiv(BB*2048*8,256),256,0,stream>>>(f1, w2, A, 2048);
  gemv_kernel<32,64,true ><<<cdiv(BB*512*8,256),256,0,stream>>>(fq1, w2, Bq, 512);
  stats_kernel<64><<<dim3(BB,4,8),256,0,stream>>>(A, Bq, idx2, 512, 2048, part);
  statsred_kernel<<<1,128,0,stream>>>(part, 8, 16.0*512*16, statsv);
  final_kernel<64><<<dim3(cdiv(512*64,256),BB),256,0,stream>>>(A, Bq, idx2, statsv, g2, be2, f2, 512, 2048);

  // ---- stage 3 compute ----
  gemv_kernel<64,64,false><<<cdiv(BB*512*8,256),256,0,stream>>>(f2, w3, A, 512);
  gemv_kernel<64,64,true ><<<cdiv(BB*512*8,256),256,0,stream>>>(f2, w3, Bq, 512);
  stats_kernel<64><<<dim3(BB,4,8),256,0,stream>>>(A, Bq, idx3, 512, 512, part);
  statsred_kernel<<<1,128,0,stream>>>(part, 8, 16.0*512*16, statsv);
  final_kernel<64><<<dim3(cdiv(512*64,256),BB),256,0,stream>>>(A, Bq, idx3, statsv, g3, be3, f3, 512, 512);

  // ---- stage 4 compute ----
  gatherf_kernel<64><<<cdiv(BB*128,256),256,0,stream>>>(fidx1, f3, fq2, 512, 128);
  gemv_kernel<64,256,false><<<cdiv(BB*512*32,256),256,0,stream>>>(f3, w4, A, 512);
  gemv_kernel<64,256,true ><<<cdiv(BB*128*32,256),256,0,stream>>>(fq2, w4, Bq, 128);
  stats_kernel<256><<<dim3(BB,4,8),256,0,stream>>>(A, Bq, idx4, 128, 512, part);
  statsred_kernel<<<1,128,0,stream>>>(part, 8, 64.0*128*16, statsv);
  final_kernel<256><<<dim3(cdiv(128*256,256),BB),256,0,stream>>>(A, Bq, idx4, statsv, g4, be4, f_out, 128, 512);
}